// Round 8
// baseline (567.548 us; speedup 1.0000x reference)
//
#include <hip/hip_runtime.h>

#define D_MODEL  1024
#define D_STATE  16
#define D_CONV   4
#define D_INNER  2048
#define DT_RANK  64
#define B_SZ     2
#define L_SEQ    4096
#define NPROJ    96                 // DT_RANK + 2*D_STATE
#define M_ROWS   (B_SZ * L_SEQ)     // 8192
#define NC       32                 // chunks over L  (R8: 64->32, halves state traffic)
#define LC       128                // steps per chunk

typedef __bf16 bf16;
typedef __bf16 bf16x8 __attribute__((ext_vector_type(8)));
typedef __bf16 bf16x4 __attribute__((ext_vector_type(4)));
typedef __bf16 bf16x2 __attribute__((ext_vector_type(2)));
typedef float  f32x4  __attribute__((ext_vector_type(4)));
typedef float  f32x2  __attribute__((ext_vector_type(2)));

// ---------------------------------------------------------------------------
// async global -> LDS, 16B per lane (wave-uniform LDS base + lane*16)
// ---------------------------------------------------------------------------
__device__ __forceinline__ void gload16(const void* g, void* l) {
    __builtin_amdgcn_global_load_lds(
        (const __attribute__((address_space(1))) unsigned int*)g,
        (__attribute__((address_space(3))) unsigned int*)l,
        16, 0, 0);
}

// ---------------------------------------------------------------------------
// fused fp32 -> bf16 converts (4 tensors, one launch)
// ---------------------------------------------------------------------------
__global__ __launch_bounds__(256)
void f2b_all(const float4* __restrict__ s0, bf16x4* __restrict__ d0, int n0,
             const float4* __restrict__ s1, bf16x4* __restrict__ d1, int n1,
             const float4* __restrict__ s2, bf16x4* __restrict__ d2, int n2,
             const float4* __restrict__ s3, bf16x4* __restrict__ d3, int n3) {
    int j = blockIdx.x * 256 + threadIdx.x;
    const float4* s; bf16x4* d;
    if (j < n0) { s = s0; d = d0; }
    else {
        j -= n0;
        if (j < n1) { s = s1; d = d1; }
        else {
            j -= n1;
            if (j < n2) { s = s2; d = d2; }
            else {
                j -= n2;
                if (j >= n3) return;
                s = s3; d = d3;
            }
        }
    }
    float4 v = s[j];
    bf16x4 o = {(bf16)v.x, (bf16)v.y, (bf16)v.z, (bf16)v.w};
    d[j] = o;
}

// x_proj_w (96 x 2048) -> bf16 padded to 128 rows (rows 96..127 zero)
__global__ __launch_bounds__(256) void f2b_pad_xproj(const float* __restrict__ in,
                                                     bf16* __restrict__ out) {
    int i = blockIdx.x * 256 + threadIdx.x;   // 128*2048 total
    int row = i >> 11, col = i & 2047;
    float v = (row < NPROJ) ? in[row * 2048 + col] : 0.f;
    out[i] = (bf16)v;
}

// xdbl fp32 -> bf16 copy (dt-GEMM input), after x_proj atomics complete
__global__ __launch_bounds__(256)
void xdbl_to_b(const float4* __restrict__ in, bf16x4* __restrict__ out, int n4) {
    int i = blockIdx.x * 256 + threadIdx.x;
    if (i < n4) {
        float4 v = in[i];
        bf16x4 o = {(bf16)v.x, (bf16)v.y, (bf16)v.z, (bf16)v.w};
        out[i] = o;
    }
}

// ---------------------------------------------------------------------------
// (WM*64) x 128 bf16 MFMA GEMM, BK=64, C = A(MxK) * B(NxK)^T, row-major.
// WM=4 -> 256x128 tile (87 FLOP/staged-byte, 2 blocks/CU — in_proj).
// WM=2 -> 128x128 (4 blocks/CU: VGPR 124/wave -> 4 waves/SIMD; LDS 32KB).
// grid.z = k-chunks (split-K); each z computes over [z*K, (z+1)*K).
// MODE 0: store bf16                               (xz)
// MODE 2: softplus(acc + bias[col]) -> bf16        (delta)
// MODE 3: store fp32
// MODE 5: atomicAdd fp32 (col < nvalid)            (x_proj, out_proj split-K)
// ---------------------------------------------------------------------------
template <int MODE, int WM>
__global__ __launch_bounds__(WM * 128, 2)
void gemm_bt(const bf16* __restrict__ A, const bf16* __restrict__ B,
             int M, int N, int K, int lda, int ldb,
             float* __restrict__ outf, bf16* __restrict__ outb,
             const float* __restrict__ bias, int ldout, int nvalid) {
    constexpr int NW      = WM * 2;         // waves per block
    constexpr int A_TILES = WM * 4;         // 16-row fragment tiles of A
    constexpr int B_TILES = 8;
    constexpr int UPW     = (A_TILES + B_TILES) * 2 / NW;  // stage units/wave

    __shared__ bf16 As[A_TILES * 2 * 64 * 8];
    __shared__ bf16 Bs[B_TILES * 2 * 64 * 8];

    const int tid  = threadIdx.x;
    const int wave = tid >> 6;
    const int lane = tid & 63;
    const int l15  = lane & 15;
    const int lk   = lane >> 4;            // 0..3  (k-group)
    const int mBase = blockIdx.y * (WM * 64);
    const int nBase = blockIdx.x * 128;
    const int koff  = blockIdx.z * K;
    const int wm    = wave >> 1;           // 0..WM-1 : 64-row slab
    const int wn    = wave & 1;            // 0..1    : 64-col half

    f32x4 acc[4][4];
    const f32x4 zz = {0.f, 0.f, 0.f, 0.f};
#pragma unroll
    for (int i = 0; i < 4; i++)
#pragma unroll
        for (int j = 0; j < 4; j++) acc[i][j] = zz;

    for (int k0 = 0; k0 < K; k0 += 64) {
#pragma unroll
        for (int u = 0; u < UPW; u++) {
            const int g = wave * UPW + u;
            const int s = g & 1;           // sub-slab (k 0..31 / 32..63)
            const int t = g >> 1;          // fragment-tile index
            if (t < A_TILES) {
                const bf16* gA = A + (size_t)(mBase + t * 16 + l15) * lda
                                   + koff + k0 + s * 32 + lk * 8;
                gload16(gA, &As[((t * 2 + s) * 64 + lane) * 8]);
            } else {
                const int nt = t - A_TILES;
                const bf16* gB = B + (size_t)(nBase + nt * 16 + l15) * ldb
                                   + koff + k0 + s * 32 + lk * 8;
                gload16(gB, &Bs[((nt * 2 + s) * 64 + lane) * 8]);
            }
        }
        __syncthreads();

#pragma unroll
        for (int s = 0; s < 2; s++) {
            bf16x8 af[4], bfr[4];
#pragma unroll
            for (int i = 0; i < 4; i++)
                af[i] = *(const bf16x8*)&As[(((wm * 4 + i) * 2 + s) * 64 + lane) * 8];
#pragma unroll
            for (int j = 0; j < 4; j++)
                bfr[j] = *(const bf16x8*)&Bs[(((wn * 4 + j) * 2 + s) * 64 + lane) * 8];
#pragma unroll
            for (int i = 0; i < 4; i++)
#pragma unroll
                for (int j = 0; j < 4; j++)
                    acc[i][j] = __builtin_amdgcn_mfma_f32_16x16x32_bf16(af[i], bfr[j],
                                                                        acc[i][j], 0, 0, 0);
        }
        __syncthreads();
    }

    // C/D layout (verified m89/m91): col = lane&15, row = (lane>>4)*4 + reg
#pragma unroll
    for (int i = 0; i < 4; i++) {
#pragma unroll
        for (int j = 0; j < 4; j++) {
            const int col = nBase + wn * 64 + j * 16 + l15;
#pragma unroll
            for (int r = 0; r < 4; r++) {
                const int row = mBase + wm * 64 + i * 16 + lk * 4 + r;
                float v = acc[i][j][r];
                if (MODE == 0) {
                    outb[(size_t)row * ldout + col] = (bf16)v;
                } else if (MODE == 2) {
                    float xv = v + bias[col];
                    float sp = fmaxf(xv, 0.f) + log1pf(expf(-fabsf(xv)));
                    outb[(size_t)row * ldout + col] = (bf16)sp;
                } else if (MODE == 3) {
                    outf[(size_t)row * ldout + col] = v;
                } else {  // MODE 5: split-K atomic accumulate
                    if (col < nvalid)
                        atomicAdd(&outf[(size_t)row * ldout + col], v);
                }
            }
        }
    }
}

// ---------------------------------------------------------------------------
// causal depthwise conv (k=4) + bias + silu, two channels per thread
// ---------------------------------------------------------------------------
__global__ __launch_bounds__(256)
void conv_silu(const bf16* __restrict__ xz, const float* __restrict__ cw,
               const float* __restrict__ cb, bf16* __restrict__ uact) {
    int i = blockIdx.x * 256 + threadIdx.x;       // b*l*(d/2)
    int dp = i & 1023;                            // channel pair
    int l  = (i >> 10) & (L_SEQ - 1);
    int b  = i >> 22;
    float4 w0 = *(const float4*)&cw[dp * 8];
    float4 w1 = *(const float4*)&cw[dp * 8 + 4];
    const float wv0[4] = {w0.x, w0.y, w0.z, w0.w};
    const float wv1[4] = {w1.x, w1.y, w1.z, w1.w};
    float2 cbv = *(const float2*)&cb[dp * 2];
    float a0 = cbv.x, a1 = cbv.y;
    size_t rb = (size_t)b * L_SEQ;
    const unsigned int* xz32 = (const unsigned int*)xz;  // row stride 2048 dwords
#pragma unroll
    for (int k = 0; k < 4; k++) {
        int li = l - 3 + k;
        if (li >= 0) {
            unsigned int u = xz32[(rb + li) * 2048 + dp];
            float lo = __uint_as_float(u << 16);
            float hi = __uint_as_float(u & 0xFFFF0000u);
            a0 += lo * wv0[k];
            a1 += hi * wv1[k];
        }
    }
    float s0 = a0 / (1.f + expf(-a0));
    float s1 = a1 / (1.f + expf(-a1));
    bf16x2 pk = {(bf16)s0, (bf16)s1};
    ((bf16x2*)uact)[(rb + l) * 1024 + dp] = pk;
}

// ---------------------------------------------------------------------------
// selective scan, chunked 2-pass. NC=32 chunks of LC=128.
// state layouts (coalesced over d):
//   hloc/h0: [b][c][n][d]   Ssum: [b][c][d]
// Fast path: A_log = log(arange(1..17)) broadcast -> A[d][n] = -(n+1):
// 1 exp + mul chain per step (runtime-verified; generic fallback kept).
// Chunk's B/C rows staged once into LDS.
// ---------------------------------------------------------------------------
__global__ __launch_bounds__(256)
void scan_passA(const bf16* __restrict__ delta, const bf16* __restrict__ uact,
                const float* __restrict__ xdbl, const float* __restrict__ A_log,
                float* __restrict__ hloc, float* __restrict__ Ssum) {
    __shared__ float sB[LC][16];          // 8 KB
    int tid = threadIdx.x, bid = blockIdx.x;
    int d = (bid & 7) * 256 + tid;
    int c = (bid >> 3) & (NC - 1);
    int b = bid >> 8;                     // 3 + log2(NC)=5 bits
    size_t rowb = (size_t)b * L_SEQ + c * LC;
    for (int i = tid; i < LC * 16; i += 256)
        sB[i >> 4][i & 15] = xdbl[(rowb + (i >> 4)) * NPROJ + DT_RANK + (i & 15)];
    float a[16];
    bool regular = true;
#pragma unroll
    for (int n = 0; n < 16; n++) {
        a[n] = expf(A_log[d * 16 + n]);                    // = n+1 expected
        regular = regular && (fabsf(a[n] - (float)(n + 1) * a[0]) < 1e-3f * (n + 1));
    }
    f32x2 h2[8];
#pragma unroll
    for (int k = 0; k < 8; k++) h2[k] = {0.f, 0.f};
    float S = 0.f;
    __syncthreads();

    if (regular) {
        const float na0 = -a[0] * 1.44269504f;             // for exp2
        for (int t = 0; t < LC; t++) {
            size_t r = rowb + t;
            float dt = (float)delta[r * D_INNER + d];
            float u  = (float)uact [r * D_INNER + d];
            S += dt;
            f32x2 du2 = {dt * u, dt * u};
            const f32x2* B2 = (const f32x2*)&sB[t][0];
            float e  = exp2f(dt * na0);                    // e^{-dt*a0}
            float e2 = e * e;
            f32x2 p  = {e, e2};
            f32x2 ee = {e2, e2};
#pragma unroll
            for (int k = 0; k < 8; k++) {
                h2[k] = h2[k] * p + du2 * B2[k];
                p = p * ee;
            }
        }
    } else {
        f32x2 An2[8];
#pragma unroll
        for (int k = 0; k < 8; k++)
            An2[k] = {-a[2 * k] * 1.44269504f, -a[2 * k + 1] * 1.44269504f};
        for (int t = 0; t < LC; t++) {
            size_t r = rowb + t;
            float dt = (float)delta[r * D_INNER + d];
            float u  = (float)uact [r * D_INNER + d];
            S += dt;
            f32x2 du2 = {dt * u, dt * u};
            const f32x2* B2 = (const f32x2*)&sB[t][0];
#pragma unroll
            for (int k = 0; k < 8; k++) {
                f32x2 dA = {exp2f(dt * An2[k][0]), exp2f(dt * An2[k][1])};
                h2[k] = h2[k] * dA + du2 * B2[k];
            }
        }
    }
    size_t cb_ = (size_t)b * NC + c;
#pragma unroll
    for (int k = 0; k < 8; k++) {
        hloc[(cb_ * 16 + 2 * k    ) * D_INNER + d] = h2[k][0];
        hloc[(cb_ * 16 + 2 * k + 1) * D_INNER + d] = h2[k][1];
    }
    Ssum[cb_ * D_INNER + d] = S;
}

// inter-chunk exclusive scan: thread per (b,d,n), d fastest (coalesced)
__global__ __launch_bounds__(256)
void scan_mid(const float* __restrict__ hloc, const float* __restrict__ Ssum,
              const float* __restrict__ A_log, float* __restrict__ h0) {
    int idx = blockIdx.x * 256 + threadIdx.x;   // 65536
    int d = idx & (D_INNER - 1);
    int n = (idx >> 11) & 15;
    int b = idx >> 15;
    float An = -expf(A_log[d * 16 + n]) * 1.44269504f;
    float H = 0.f;
    for (int c = 0; c < NC; c++) {
        size_t cb_ = (size_t)b * NC + c;
        h0[(cb_ * 16 + n) * D_INNER + d] = H;
        H = H * exp2f(Ssum[cb_ * D_INNER + d] * An)
          + hloc[(cb_ * 16 + n) * D_INNER + d];
    }
}

// pass B: recompute h with true h0, emit y = (C.h + u*Dp) * silu(z) as bf16
__global__ __launch_bounds__(256)
void scan_passB(const bf16* __restrict__ delta, const bf16* __restrict__ uact,
                const float* __restrict__ xdbl, const float* __restrict__ A_log,
                const float* __restrict__ h0, const float* __restrict__ Dp,
                const bf16* __restrict__ xz, bf16* __restrict__ y) {
    __shared__ float sBC[LC][32];         // 16 KB: B then C per row
    int tid = threadIdx.x, bid = blockIdx.x;
    int d = (bid & 7) * 256 + tid;
    int c = (bid >> 3) & (NC - 1);
    int b = bid >> 8;
    size_t rowb = (size_t)b * L_SEQ + c * LC;
    for (int i = tid; i < LC * 32; i += 256)
        sBC[i >> 5][i & 31] = xdbl[(rowb + (i >> 5)) * NPROJ + DT_RANK + (i & 31)];
    float a[16];
    bool regular = true;
#pragma unroll
    for (int n = 0; n < 16; n++) {
        a[n] = expf(A_log[d * 16 + n]);
        regular = regular && (fabsf(a[n] - (float)(n + 1) * a[0]) < 1e-3f * (n + 1));
    }
    size_t cb_ = (size_t)b * NC + c;
    f32x2 h2[8];
#pragma unroll
    for (int k = 0; k < 8; k++) {
        h2[k][0] = h0[(cb_ * 16 + 2 * k    ) * D_INNER + d];
        h2[k][1] = h0[(cb_ * 16 + 2 * k + 1) * D_INNER + d];
    }
    float Dd = Dp[d];
    __syncthreads();

    if (regular) {
        const float na0 = -a[0] * 1.44269504f;
        for (int t = 0; t < LC; t++) {
            size_t r = rowb + t;
            float dt = (float)delta[r * D_INNER + d];
            float u  = (float)uact [r * D_INNER + d];
            f32x2 du2 = {dt * u, dt * u};
            const f32x2* B2 = (const f32x2*)&sBC[t][0];
            const f32x2* C2 = (const f32x2*)&sBC[t][16];
            float e  = exp2f(dt * na0);
            float e2 = e * e;
            f32x2 p  = {e, e2};
            f32x2 ee = {e2, e2};
            f32x2 yt2 = {0.f, 0.f};
#pragma unroll
            for (int k = 0; k < 8; k++) {
                h2[k] = h2[k] * p + du2 * B2[k];
                yt2 = yt2 + h2[k] * C2[k];
                p = p * ee;
            }
            float yt = yt2[0] + yt2[1] + u * Dd;
            float z = (float)xz[r * (2 * D_INNER) + D_INNER + d];
            float g = z / (1.f + expf(-z));
            y[r * D_INNER + d] = (bf16)(yt * g);
        }
    } else {
        f32x2 An2[8];
#pragma unroll
        for (int k = 0; k < 8; k++)
            An2[k] = {-a[2 * k] * 1.44269504f, -a[2 * k + 1] * 1.44269504f};
        for (int t = 0; t < LC; t++) {
            size_t r = rowb + t;
            float dt = (float)delta[r * D_INNER + d];
            float u  = (float)uact [r * D_INNER + d];
            f32x2 du2 = {dt * u, dt * u};
            const f32x2* B2 = (const f32x2*)&sBC[t][0];
            const f32x2* C2 = (const f32x2*)&sBC[t][16];
            f32x2 yt2 = {0.f, 0.f};
#pragma unroll
            for (int k = 0; k < 8; k++) {
                f32x2 dA = {exp2f(dt * An2[k][0]), exp2f(dt * An2[k][1])};
                h2[k] = h2[k] * dA + du2 * B2[k];
                yt2 = yt2 + h2[k] * C2[k];
            }
            float yt = yt2[0] + yt2[1] + u * Dd;
            float z = (float)xz[r * (2 * D_INNER) + D_INNER + d];
            float g = z / (1.f + expf(-z));
            y[r * D_INNER + d] = (bf16)(yt * g);
        }
    }
}

// ---------------------------------------------------------------------------
extern "C" void kernel_launch(void* const* d_in, const int* in_sizes, int n_in,
                              void* d_out, int out_size, void* d_ws, size_t ws_size,
                              hipStream_t stream) {
    const float* x         = (const float*)d_in[0];
    const float* in_proj_w = (const float*)d_in[1];
    const float* conv_w    = (const float*)d_in[2];
    const float* conv_b    = (const float*)d_in[3];
    const float* x_proj_w  = (const float*)d_in[4];
    const float* dt_proj_w = (const float*)d_in[5];
    const float* dt_proj_b = (const float*)d_in[6];
    const float* A_log     = (const float*)d_in[7];
    const float* Dp        = (const float*)d_in[8];
    const float* out_proj_w= (const float*)d_in[9];
    float* out             = (float*)d_out;

    char* p = (char*)d_ws;
    auto alloc = [&](size_t bytes) -> char* {
        char* r = p;
        p += (bytes + 255) & ~(size_t)255;
        return r;
    };
    bf16*  x_bf    = (bf16*) alloc((size_t)M_ROWS * D_MODEL * 2);      // 16 MB
    bf16*  w_in    = (bf16*) alloc((size_t)2 * D_INNER * D_MODEL * 2); // 8 MB
    bf16*  w_xp    = (bf16*) alloc((size_t)128 * D_INNER * 2);         // 0.5 MB
    bf16*  w_dt    = (bf16*) alloc((size_t)D_INNER * DT_RANK * 2);     // 0.25 MB
    bf16*  w_out   = (bf16*) alloc((size_t)D_MODEL * D_INNER * 2);     // 4 MB
    bf16*  xz      = (bf16*) alloc((size_t)M_ROWS * 2 * D_INNER * 2);  // 64 MB
    bf16*  uact    = (bf16*) alloc((size_t)M_ROWS * D_INNER * 2);      // 32 MB
    float* xdbl    = (float*)alloc((size_t)M_ROWS * NPROJ * 4);        // 3 MB
    bf16*  xdbl_b  = (bf16*) alloc((size_t)M_ROWS * NPROJ * 2);        // 1.5 MB
    bf16*  deltab  = (bf16*) alloc((size_t)M_ROWS * D_INNER * 2);      // 32 MB
    float* hloc    = (float*)alloc((size_t)B_SZ * NC * 16 * D_INNER * 4); // 8 MB
    float* Ssum    = (float*)alloc((size_t)B_SZ * NC * D_INNER * 4);   // 1 MB
    float* h0      = (float*)alloc((size_t)B_SZ * NC * 16 * D_INNER * 4); // 8 MB
    bf16*  ybf     = (bf16*) alloc((size_t)M_ROWS * D_INNER * 2);      // 32 MB

    // 0) zero accumulation targets (split-K atomic epilogues)
    hipMemsetAsync(xdbl, 0, (size_t)M_ROWS * NPROJ * 4, stream);
    hipMemsetAsync(out, 0, (size_t)M_ROWS * D_MODEL * 4, stream);

    // 1) converts (one fused launch + xproj pad)
    {
        const int n0 = M_ROWS * D_MODEL / 4;          // x
        const int n1 = 2 * D_INNER * D_MODEL / 4;     // in_proj_w
        const int n2 = D_INNER * DT_RANK / 4;         // dt_proj_w
        const int n3 = D_MODEL * D_INNER / 4;         // out_proj_w
        const int nt = n0 + n1 + n2 + n3;
        f2b_all<<<(nt + 255) / 256, 256, 0, stream>>>(
            (const float4*)x, (bf16x4*)x_bf, n0,
            (const float4*)in_proj_w, (bf16x4*)w_in, n1,
            (const float4*)dt_proj_w, (bf16x4*)w_dt, n2,
            (const float4*)out_proj_w, (bf16x4*)w_out, n3);
        f2b_pad_xproj<<<(128 * D_INNER) / 256, 256, 0, stream>>>(x_proj_w, w_xp);
    }

    // 2) in_proj: xz = x @ in_proj_w^T   (8192 x 4096, K=1024), 256x128 tiles
    gemm_bt<0, 4><<<dim3(2 * D_INNER / 128, M_ROWS / 256, 1), 512, 0, stream>>>(
        x_bf, w_in, M_ROWS, 2 * D_INNER, D_MODEL, D_MODEL, D_MODEL,
        nullptr, xz, nullptr, 2 * D_INNER, 2 * D_INNER);

    // 3) conv + silu -> u_act
    conv_silu<<<(M_ROWS * D_INNER / 2) / 256, 256, 0, stream>>>(xz, conv_w, conv_b, uact);

    // 4) x_proj split-K(4), atomic epilogue into xdbl fp32 (cols<96)
    gemm_bt<5, 2><<<dim3(1, M_ROWS / 128, 4), 256, 0, stream>>>(
        uact, w_xp, M_ROWS, 128, 512, D_INNER, D_INNER,
        xdbl, nullptr, nullptr, NPROJ, NPROJ);
    xdbl_to_b<<<(M_ROWS * NPROJ / 4 + 255) / 256, 256, 0, stream>>>(
        (const float4*)xdbl, (bf16x4*)xdbl_b, M_ROWS * NPROJ / 4);

    // 5) dt: delta = softplus(x_dbl[:, :64] @ dt_proj_w^T + b)
    //    K=64 (single iter) -> WM=2, 1024 blocks = 4/CU
    gemm_bt<2, 2><<<dim3(D_INNER / 128, M_ROWS / 128, 1), 256, 0, stream>>>(
        xdbl_b, w_dt, M_ROWS, D_INNER, DT_RANK, NPROJ, DT_RANK,
        nullptr, deltab, dt_proj_b, D_INNER, D_INNER);

    // 6) scan (NC=32 chunks of LC=128)
    scan_passA<<<B_SZ * NC * (D_INNER / 256), 256, 0, stream>>>(
        deltab, uact, xdbl, A_log, hloc, Ssum);
    scan_mid<<<(B_SZ * D_INNER * 16) / 256, 256, 0, stream>>>(hloc, Ssum, A_log, h0);
    scan_passB<<<B_SZ * NC * (D_INNER / 256), 256, 0, stream>>>(
        deltab, uact, xdbl, A_log, h0, Dp, xz, ybf);

    // 7) out_proj -> d_out (fp32), split-K=2, WM=2: 1024 blocks = 4/CU
    gemm_bt<5, 2><<<dim3(D_MODEL / 128, M_ROWS / 128, 2), 256, 0, stream>>>(
        ybf, w_out, M_ROWS, D_MODEL, 1024, D_INNER, D_INNER,
        out, nullptr, nullptr, D_MODEL, D_MODEL);

    (void)in_sizes; (void)n_in; (void)out_size; (void)ws_size;
}

// Round 9
// 513.621 us; speedup vs baseline: 1.1050x; 1.1050x over previous
//
#include <hip/hip_runtime.h>

#define D_MODEL  1024
#define D_STATE  16
#define D_CONV   4
#define D_INNER  2048
#define DT_RANK  64
#define B_SZ     2
#define L_SEQ    4096
#define NPROJ    96                 // DT_RANK + 2*D_STATE
#define M_ROWS   (B_SZ * L_SEQ)     // 8192
#define NC       32                 // chunks over L (halved state traffic vs 64)
#define LC       128                // steps per chunk

typedef __bf16 bf16;
typedef __bf16 bf16x8 __attribute__((ext_vector_type(8)));
typedef __bf16 bf16x4 __attribute__((ext_vector_type(4)));
typedef __bf16 bf16x2 __attribute__((ext_vector_type(2)));
typedef float  f32x4  __attribute__((ext_vector_type(4)));
typedef float  f32x2  __attribute__((ext_vector_type(2)));

// ---------------------------------------------------------------------------
// async global -> LDS, 16B per lane (wave-uniform LDS base + lane*16)
// ---------------------------------------------------------------------------
__device__ __forceinline__ void gload16(const void* g, void* l) {
    __builtin_amdgcn_global_load_lds(
        (const __attribute__((address_space(1))) unsigned int*)g,
        (__attribute__((address_space(3))) unsigned int*)l,
        16, 0, 0);
}

// ---------------------------------------------------------------------------
// fused fp32 -> bf16 converts (4 tensors, one launch)
// ---------------------------------------------------------------------------
__global__ __launch_bounds__(256)
void f2b_all(const float4* __restrict__ s0, bf16x4* __restrict__ d0, int n0,
             const float4* __restrict__ s1, bf16x4* __restrict__ d1, int n1,
             const float4* __restrict__ s2, bf16x4* __restrict__ d2, int n2,
             const float4* __restrict__ s3, bf16x4* __restrict__ d3, int n3) {
    int j = blockIdx.x * 256 + threadIdx.x;
    const float4* s; bf16x4* d;
    if (j < n0) { s = s0; d = d0; }
    else {
        j -= n0;
        if (j < n1) { s = s1; d = d1; }
        else {
            j -= n1;
            if (j < n2) { s = s2; d = d2; }
            else {
                j -= n2;
                if (j >= n3) return;
                s = s3; d = d3;
            }
        }
    }
    float4 v = s[j];
    bf16x4 o = {(bf16)v.x, (bf16)v.y, (bf16)v.z, (bf16)v.w};
    d[j] = o;
}

// x_proj_w (96 x 2048) -> bf16 padded to 128 rows (rows 96..127 zero)
__global__ __launch_bounds__(256) void f2b_pad_xproj(const float* __restrict__ in,
                                                     bf16* __restrict__ out) {
    int i = blockIdx.x * 256 + threadIdx.x;   // 128*2048 total
    int row = i >> 11, col = i & 2047;
    float v = (row < NPROJ) ? in[row * 2048 + col] : 0.f;
    out[i] = (bf16)v;
}

// ---------------------------------------------------------------------------
// (WM*64) x 128 bf16 MFMA GEMM, BK=64, C = A(MxK) * B(NxK)^T, row-major.
// WM=4 -> 256x128 tile (2 blocks/CU — in_proj); WM=2 -> 128x128 (4 blocks/CU).
// [R8 falsified: atomicAdd split-K epilogue = 2x FETCH (L2 RMW) + serialized
//  epilogue, out_proj 65->112 µs. Reverted to MODE 3/4 stores.]
// grid.z = k-chunks (split-K via partial buffer); z computes [z*K,(z+1)*K).
// MODE 0: store bf16                             (xz)
// MODE 2: softplus(acc + bias[col]) -> bf16      (delta)
// MODE 3: store fp32                             (final out)
// MODE 4: store fp32 partial at z-slice, ld=128  (x_proj split-K)
// ---------------------------------------------------------------------------
template <int MODE, int WM>
__global__ __launch_bounds__(WM * 128, 2)
void gemm_bt(const bf16* __restrict__ A, const bf16* __restrict__ B,
             int M, int N, int K, int lda, int ldb,
             float* __restrict__ outf, bf16* __restrict__ outb,
             const float* __restrict__ bias, int ldout) {
    constexpr int NW      = WM * 2;         // waves per block
    constexpr int A_TILES = WM * 4;         // 16-row fragment tiles of A
    constexpr int B_TILES = 8;
    constexpr int UPW     = (A_TILES + B_TILES) * 2 / NW;  // stage units/wave

    __shared__ bf16 As[A_TILES * 2 * 64 * 8];
    __shared__ bf16 Bs[B_TILES * 2 * 64 * 8];

    const int tid  = threadIdx.x;
    const int wave = tid >> 6;
    const int lane = tid & 63;
    const int l15  = lane & 15;
    const int lk   = lane >> 4;            // 0..3  (k-group)
    const int mBase = blockIdx.y * (WM * 64);
    const int nBase = blockIdx.x * 128;
    const int koff  = blockIdx.z * K;
    const int wm    = wave >> 1;           // 0..WM-1 : 64-row slab
    const int wn    = wave & 1;            // 0..1    : 64-col half

    f32x4 acc[4][4];
    const f32x4 zz = {0.f, 0.f, 0.f, 0.f};
#pragma unroll
    for (int i = 0; i < 4; i++)
#pragma unroll
        for (int j = 0; j < 4; j++) acc[i][j] = zz;

    for (int k0 = 0; k0 < K; k0 += 64) {
#pragma unroll
        for (int u = 0; u < UPW; u++) {
            const int g = wave * UPW + u;
            const int s = g & 1;           // sub-slab (k 0..31 / 32..63)
            const int t = g >> 1;          // fragment-tile index
            if (t < A_TILES) {
                const bf16* gA = A + (size_t)(mBase + t * 16 + l15) * lda
                                   + koff + k0 + s * 32 + lk * 8;
                gload16(gA, &As[((t * 2 + s) * 64 + lane) * 8]);
            } else {
                const int nt = t - A_TILES;
                const bf16* gB = B + (size_t)(nBase + nt * 16 + l15) * ldb
                                   + koff + k0 + s * 32 + lk * 8;
                gload16(gB, &Bs[((nt * 2 + s) * 64 + lane) * 8]);
            }
        }
        __syncthreads();

#pragma unroll
        for (int s = 0; s < 2; s++) {
            bf16x8 af[4], bfr[4];
#pragma unroll
            for (int i = 0; i < 4; i++)
                af[i] = *(const bf16x8*)&As[(((wm * 4 + i) * 2 + s) * 64 + lane) * 8];
#pragma unroll
            for (int j = 0; j < 4; j++)
                bfr[j] = *(const bf16x8*)&Bs[(((wn * 4 + j) * 2 + s) * 64 + lane) * 8];
#pragma unroll
            for (int i = 0; i < 4; i++)
#pragma unroll
                for (int j = 0; j < 4; j++)
                    acc[i][j] = __builtin_amdgcn_mfma_f32_16x16x32_bf16(af[i], bfr[j],
                                                                        acc[i][j], 0, 0, 0);
        }
        __syncthreads();
    }

    // C/D layout (verified m89/m91): col = lane&15, row = (lane>>4)*4 + reg
#pragma unroll
    for (int i = 0; i < 4; i++) {
#pragma unroll
        for (int j = 0; j < 4; j++) {
            const int col = nBase + wn * 64 + j * 16 + l15;
#pragma unroll
            for (int r = 0; r < 4; r++) {
                const int row = mBase + wm * 64 + i * 16 + lk * 4 + r;
                float v = acc[i][j][r];
                if (MODE == 0) {
                    outb[(size_t)row * ldout + col] = (bf16)v;
                } else if (MODE == 2) {
                    float xv = v + bias[col];
                    float sp = fmaxf(xv, 0.f) + log1pf(expf(-fabsf(xv)));
                    outb[(size_t)row * ldout + col] = (bf16)sp;
                } else if (MODE == 3) {
                    outf[(size_t)row * ldout + col] = v;
                } else {  // MODE 4
                    outf[((size_t)blockIdx.z * M + row) * 128 + col] = v;
                }
            }
        }
    }
}

// reduce 4 split-K partials (each [M][128]) -> xdbl fp32 [M][96] + bf16 copy
__global__ __launch_bounds__(256)
void reduce_xproj(const float* __restrict__ part, float* __restrict__ xdbl,
                  bf16* __restrict__ xdbl_b) {
    int i = blockIdx.x * 256 + threadIdx.x;   // M_ROWS * 96
    if (i >= M_ROWS * NPROJ) return;
    int row = i / NPROJ;
    int col = i - row * NPROJ;
    size_t o = (size_t)row * 128 + col;
    float s = part[o] + part[(size_t)M_ROWS * 128 + o]
            + part[(size_t)2 * M_ROWS * 128 + o] + part[(size_t)3 * M_ROWS * 128 + o];
    xdbl[i] = s;
    xdbl_b[i] = (bf16)s;
}

// ---------------------------------------------------------------------------
// causal depthwise conv (k=4) + bias + silu, two channels per thread
// ---------------------------------------------------------------------------
__global__ __launch_bounds__(256)
void conv_silu(const bf16* __restrict__ xz, const float* __restrict__ cw,
               const float* __restrict__ cb, bf16* __restrict__ uact) {
    int i = blockIdx.x * 256 + threadIdx.x;       // b*l*(d/2)
    int dp = i & 1023;                            // channel pair
    int l  = (i >> 10) & (L_SEQ - 1);
    int b  = i >> 22;
    float4 w0 = *(const float4*)&cw[dp * 8];
    float4 w1 = *(const float4*)&cw[dp * 8 + 4];
    const float wv0[4] = {w0.x, w0.y, w0.z, w0.w};
    const float wv1[4] = {w1.x, w1.y, w1.z, w1.w};
    float2 cbv = *(const float2*)&cb[dp * 2];
    float a0 = cbv.x, a1 = cbv.y;
    size_t rb = (size_t)b * L_SEQ;
    const unsigned int* xz32 = (const unsigned int*)xz;  // row stride 2048 dwords
#pragma unroll
    for (int k = 0; k < 4; k++) {
        int li = l - 3 + k;
        if (li >= 0) {
            unsigned int u = xz32[(rb + li) * 2048 + dp];
            float lo = __uint_as_float(u << 16);
            float hi = __uint_as_float(u & 0xFFFF0000u);
            a0 += lo * wv0[k];
            a1 += hi * wv1[k];
        }
    }
    float s0 = a0 / (1.f + expf(-a0));
    float s1 = a1 / (1.f + expf(-a1));
    bf16x2 pk = {(bf16)s0, (bf16)s1};
    ((bf16x2*)uact)[(rb + l) * 1024 + dp] = pk;
}

// ---------------------------------------------------------------------------
// selective scan, chunked 2-pass. NC=32 chunks of LC=128.
// state layouts (coalesced over d):
//   hloc/h0: [b][c][n][d]   Ssum: [b][c][d]
// Fast path: A_log = log(arange(1..17)) broadcast -> A[d][n] = -(n+1):
// 1 exp + mul chain per step (runtime-verified; generic fallback kept).
// Chunk's B/C rows staged once into LDS.
// ---------------------------------------------------------------------------
__global__ __launch_bounds__(256)
void scan_passA(const bf16* __restrict__ delta, const bf16* __restrict__ uact,
                const float* __restrict__ xdbl, const float* __restrict__ A_log,
                float* __restrict__ hloc, float* __restrict__ Ssum) {
    __shared__ float sB[LC][16];          // 8 KB
    int tid = threadIdx.x, bid = blockIdx.x;
    int d = (bid & 7) * 256 + tid;
    int c = (bid >> 3) & (NC - 1);
    int b = bid >> 8;                     // 3 + log2(NC)=5 bits
    size_t rowb = (size_t)b * L_SEQ + c * LC;
    for (int i = tid; i < LC * 16; i += 256)
        sB[i >> 4][i & 15] = xdbl[(rowb + (i >> 4)) * NPROJ + DT_RANK + (i & 15)];
    float a[16];
    bool regular = true;
#pragma unroll
    for (int n = 0; n < 16; n++) {
        a[n] = expf(A_log[d * 16 + n]);                    // = n+1 expected
        regular = regular && (fabsf(a[n] - (float)(n + 1) * a[0]) < 1e-3f * (n + 1));
    }
    f32x2 h2[8];
#pragma unroll
    for (int k = 0; k < 8; k++) h2[k] = {0.f, 0.f};
    float S = 0.f;
    __syncthreads();

    if (regular) {
        const float na0 = -a[0] * 1.44269504f;             // for exp2
        for (int t = 0; t < LC; t++) {
            size_t r = rowb + t;
            float dt = (float)delta[r * D_INNER + d];
            float u  = (float)uact [r * D_INNER + d];
            S += dt;
            f32x2 du2 = {dt * u, dt * u};
            const f32x2* B2 = (const f32x2*)&sB[t][0];
            float e  = exp2f(dt * na0);                    // e^{-dt*a0}
            float e2 = e * e;
            f32x2 p  = {e, e2};
            f32x2 ee = {e2, e2};
#pragma unroll
            for (int k = 0; k < 8; k++) {
                h2[k] = h2[k] * p + du2 * B2[k];
                p = p * ee;
            }
        }
    } else {
        f32x2 An2[8];
#pragma unroll
        for (int k = 0; k < 8; k++)
            An2[k] = {-a[2 * k] * 1.44269504f, -a[2 * k + 1] * 1.44269504f};
        for (int t = 0; t < LC; t++) {
            size_t r = rowb + t;
            float dt = (float)delta[r * D_INNER + d];
            float u  = (float)uact [r * D_INNER + d];
            S += dt;
            f32x2 du2 = {dt * u, dt * u};
            const f32x2* B2 = (const f32x2*)&sB[t][0];
#pragma unroll
            for (int k = 0; k < 8; k++) {
                f32x2 dA = {exp2f(dt * An2[k][0]), exp2f(dt * An2[k][1])};
                h2[k] = h2[k] * dA + du2 * B2[k];
            }
        }
    }
    size_t cb_ = (size_t)b * NC + c;
#pragma unroll
    for (int k = 0; k < 8; k++) {
        hloc[(cb_ * 16 + 2 * k    ) * D_INNER + d] = h2[k][0];
        hloc[(cb_ * 16 + 2 * k + 1) * D_INNER + d] = h2[k][1];
    }
    Ssum[cb_ * D_INNER + d] = S;
}

// inter-chunk exclusive scan: thread per (b,d,n), d fastest (coalesced)
__global__ __launch_bounds__(256)
void scan_mid(const float* __restrict__ hloc, const float* __restrict__ Ssum,
              const float* __restrict__ A_log, float* __restrict__ h0) {
    int idx = blockIdx.x * 256 + threadIdx.x;   // 65536
    int d = idx & (D_INNER - 1);
    int n = (idx >> 11) & 15;
    int b = idx >> 15;
    float An = -expf(A_log[d * 16 + n]) * 1.44269504f;
    float H = 0.f;
    for (int c = 0; c < NC; c++) {
        size_t cb_ = (size_t)b * NC + c;
        h0[(cb_ * 16 + n) * D_INNER + d] = H;
        H = H * exp2f(Ssum[cb_ * D_INNER + d] * An)
          + hloc[(cb_ * 16 + n) * D_INNER + d];
    }
}

// pass B: recompute h with true h0, emit y = (C.h + u*Dp) * silu(z) as bf16
__global__ __launch_bounds__(256)
void scan_passB(const bf16* __restrict__ delta, const bf16* __restrict__ uact,
                const float* __restrict__ xdbl, const float* __restrict__ A_log,
                const float* __restrict__ h0, const float* __restrict__ Dp,
                const bf16* __restrict__ xz, bf16* __restrict__ y) {
    __shared__ float sBC[LC][32];         // 16 KB: B then C per row
    int tid = threadIdx.x, bid = blockIdx.x;
    int d = (bid & 7) * 256 + tid;
    int c = (bid >> 3) & (NC - 1);
    int b = bid >> 8;
    size_t rowb = (size_t)b * L_SEQ + c * LC;
    for (int i = tid; i < LC * 32; i += 256)
        sBC[i >> 5][i & 31] = xdbl[(rowb + (i >> 5)) * NPROJ + DT_RANK + (i & 31)];
    float a[16];
    bool regular = true;
#pragma unroll
    for (int n = 0; n < 16; n++) {
        a[n] = expf(A_log[d * 16 + n]);
        regular = regular && (fabsf(a[n] - (float)(n + 1) * a[0]) < 1e-3f * (n + 1));
    }
    size_t cb_ = (size_t)b * NC + c;
    f32x2 h2[8];
#pragma unroll
    for (int k = 0; k < 8; k++) {
        h2[k][0] = h0[(cb_ * 16 + 2 * k    ) * D_INNER + d];
        h2[k][1] = h0[(cb_ * 16 + 2 * k + 1) * D_INNER + d];
    }
    float Dd = Dp[d];
    __syncthreads();

    if (regular) {
        const float na0 = -a[0] * 1.44269504f;
        for (int t = 0; t < LC; t++) {
            size_t r = rowb + t;
            float dt = (float)delta[r * D_INNER + d];
            float u  = (float)uact [r * D_INNER + d];
            f32x2 du2 = {dt * u, dt * u};
            const f32x2* B2 = (const f32x2*)&sBC[t][0];
            const f32x2* C2 = (const f32x2*)&sBC[t][16];
            float e  = exp2f(dt * na0);
            float e2 = e * e;
            f32x2 p  = {e, e2};
            f32x2 ee = {e2, e2};
            f32x2 yt2 = {0.f, 0.f};
#pragma unroll
            for (int k = 0; k < 8; k++) {
                h2[k] = h2[k] * p + du2 * B2[k];
                yt2 = yt2 + h2[k] * C2[k];
                p = p * ee;
            }
            float yt = yt2[0] + yt2[1] + u * Dd;
            float z = (float)xz[r * (2 * D_INNER) + D_INNER + d];
            float g = z / (1.f + expf(-z));
            y[r * D_INNER + d] = (bf16)(yt * g);
        }
    } else {
        f32x2 An2[8];
#pragma unroll
        for (int k = 0; k < 8; k++)
            An2[k] = {-a[2 * k] * 1.44269504f, -a[2 * k + 1] * 1.44269504f};
        for (int t = 0; t < LC; t++) {
            size_t r = rowb + t;
            float dt = (float)delta[r * D_INNER + d];
            float u  = (float)uact [r * D_INNER + d];
            f32x2 du2 = {dt * u, dt * u};
            const f32x2* B2 = (const f32x2*)&sBC[t][0];
            const f32x2* C2 = (const f32x2*)&sBC[t][16];
            f32x2 yt2 = {0.f, 0.f};
#pragma unroll
            for (int k = 0; k < 8; k++) {
                f32x2 dA = {exp2f(dt * An2[k][0]), exp2f(dt * An2[k][1])};
                h2[k] = h2[k] * dA + du2 * B2[k];
                yt2 = yt2 + h2[k] * C2[k];
            }
            float yt = yt2[0] + yt2[1] + u * Dd;
            float z = (float)xz[r * (2 * D_INNER) + D_INNER + d];
            float g = z / (1.f + expf(-z));
            y[r * D_INNER + d] = (bf16)(yt * g);
        }
    }
}

// ---------------------------------------------------------------------------
extern "C" void kernel_launch(void* const* d_in, const int* in_sizes, int n_in,
                              void* d_out, int out_size, void* d_ws, size_t ws_size,
                              hipStream_t stream) {
    const float* x         = (const float*)d_in[0];
    const float* in_proj_w = (const float*)d_in[1];
    const float* conv_w    = (const float*)d_in[2];
    const float* conv_b    = (const float*)d_in[3];
    const float* x_proj_w  = (const float*)d_in[4];
    const float* dt_proj_w = (const float*)d_in[5];
    const float* dt_proj_b = (const float*)d_in[6];
    const float* A_log     = (const float*)d_in[7];
    const float* Dp        = (const float*)d_in[8];
    const float* out_proj_w= (const float*)d_in[9];
    float* out             = (float*)d_out;

    char* p = (char*)d_ws;
    auto alloc = [&](size_t bytes) -> char* {
        char* r = p;
        p += (bytes + 255) & ~(size_t)255;
        return r;
    };
    bf16*  x_bf    = (bf16*) alloc((size_t)M_ROWS * D_MODEL * 2);      // 16 MB
    bf16*  w_in    = (bf16*) alloc((size_t)2 * D_INNER * D_MODEL * 2); // 8 MB
    bf16*  w_xp    = (bf16*) alloc((size_t)128 * D_INNER * 2);         // 0.5 MB
    bf16*  w_dt    = (bf16*) alloc((size_t)D_INNER * DT_RANK * 2);     // 0.25 MB
    bf16*  w_out   = (bf16*) alloc((size_t)D_MODEL * D_INNER * 2);     // 4 MB
    bf16*  xz      = (bf16*) alloc((size_t)M_ROWS * 2 * D_INNER * 2);  // 64 MB
    bf16*  uact    = (bf16*) alloc((size_t)M_ROWS * D_INNER * 2);      // 32 MB
    float* xdbl    = (float*)alloc((size_t)M_ROWS * NPROJ * 4);        // 3 MB
    bf16*  xdbl_b  = (bf16*) alloc((size_t)M_ROWS * NPROJ * 2);        // 1.5 MB
    bf16*  deltab  = (bf16*) alloc((size_t)M_ROWS * D_INNER * 2);      // 32 MB
    float* hloc    = (float*)alloc((size_t)B_SZ * NC * 16 * D_INNER * 4); // 8 MB
    float* Ssum    = (float*)alloc((size_t)B_SZ * NC * D_INNER * 4);   // 1 MB
    float* h0      = (float*)alloc((size_t)B_SZ * NC * 16 * D_INNER * 4); // 8 MB
    bf16*  ybf     = (bf16*) alloc((size_t)M_ROWS * D_INNER * 2);      // 32 MB
    float* partial = (float*)alloc((size_t)4 * M_ROWS * 128 * 4);      // 16 MB

    // 1) converts (one fused launch + xproj pad)
    {
        const int n0 = M_ROWS * D_MODEL / 4;          // x
        const int n1 = 2 * D_INNER * D_MODEL / 4;     // in_proj_w
        const int n2 = D_INNER * DT_RANK / 4;         // dt_proj_w
        const int n3 = D_MODEL * D_INNER / 4;         // out_proj_w
        const int nt = n0 + n1 + n2 + n3;
        f2b_all<<<(nt + 255) / 256, 256, 0, stream>>>(
            (const float4*)x, (bf16x4*)x_bf, n0,
            (const float4*)in_proj_w, (bf16x4*)w_in, n1,
            (const float4*)dt_proj_w, (bf16x4*)w_dt, n2,
            (const float4*)out_proj_w, (bf16x4*)w_out, n3);
        f2b_pad_xproj<<<(128 * D_INNER) / 256, 256, 0, stream>>>(x_proj_w, w_xp);
    }

    // 2) in_proj: xz = x @ in_proj_w^T   (8192 x 4096, K=1024), 256x128 tiles
    gemm_bt<0, 4><<<dim3(2 * D_INNER / 128, M_ROWS / 256, 1), 512, 0, stream>>>(
        x_bf, w_in, M_ROWS, 2 * D_INNER, D_MODEL, D_MODEL, D_MODEL,
        nullptr, xz, nullptr, 2 * D_INNER);

    // 3) conv + silu -> u_act
    conv_silu<<<(M_ROWS * D_INNER / 2) / 256, 256, 0, stream>>>(xz, conv_w, conv_b, uact);

    // 4) x_proj split-K(4): partials = u_act @ x_proj_w^T  (8192 x 128, K=4x512)
    gemm_bt<4, 2><<<dim3(1, M_ROWS / 128, 4), 256, 0, stream>>>(
        uact, w_xp, M_ROWS, 128, 512, D_INNER, D_INNER,
        partial, nullptr, nullptr, 128);
    reduce_xproj<<<(M_ROWS * NPROJ + 255) / 256, 256, 0, stream>>>(partial, xdbl, xdbl_b);

    // 5) dt: delta = softplus(x_dbl[:, :64] @ dt_proj_w^T + b)
    //    K=64 single-iter -> WM=2, 1024 blocks = 4/CU
    gemm_bt<2, 2><<<dim3(D_INNER / 128, M_ROWS / 128, 1), 256, 0, stream>>>(
        xdbl_b, w_dt, M_ROWS, D_INNER, DT_RANK, NPROJ, DT_RANK,
        nullptr, deltab, dt_proj_b, D_INNER);

    // 6) scan (NC=32 chunks of LC=128)
    scan_passA<<<B_SZ * NC * (D_INNER / 256), 256, 0, stream>>>(
        deltab, uact, xdbl, A_log, hloc, Ssum);
    scan_mid<<<(B_SZ * D_INNER * 16) / 256, 256, 0, stream>>>(hloc, Ssum, A_log, h0);
    scan_passB<<<B_SZ * NC * (D_INNER / 256), 256, 0, stream>>>(
        deltab, uact, xdbl, A_log, h0, Dp, xz, ybf);

    // 7) out_proj -> d_out (fp32), 128x128 tiles, 512 blocks = 2/CU (R7 form)
    gemm_bt<3, 2><<<dim3(D_MODEL / 128, M_ROWS / 128, 1), 256, 0, stream>>>(
        ybf, w_out, M_ROWS, D_MODEL, D_INNER, D_INNER, D_INNER,
        out, nullptr, nullptr, D_MODEL);

    (void)in_sizes; (void)n_in; (void)out_size; (void)ws_size;
}

// Round 10
// 495.053 us; speedup vs baseline: 1.1464x; 1.0375x over previous
//
#include <hip/hip_runtime.h>

#define D_MODEL  1024
#define D_STATE  16
#define D_CONV   4
#define D_INNER  2048
#define DT_RANK  64
#define B_SZ     2
#define L_SEQ    4096
#define NPROJ    96                 // DT_RANK + 2*D_STATE
#define M_ROWS   (B_SZ * L_SEQ)     // 8192
#define NC       64                 // chunks over L (R9 falsified NC=32: scan is
#define LC       64                 //  latency-bound; TLP > state-traffic saving)

typedef __bf16 bf16;
typedef __bf16 bf16x8 __attribute__((ext_vector_type(8)));
typedef __bf16 bf16x4 __attribute__((ext_vector_type(4)));
typedef __bf16 bf16x2 __attribute__((ext_vector_type(2)));
typedef float  f32x4  __attribute__((ext_vector_type(4)));
typedef float  f32x2  __attribute__((ext_vector_type(2)));

// ---------------------------------------------------------------------------
// async global -> LDS, 16B per lane (wave-uniform LDS base + lane*16)
// ---------------------------------------------------------------------------
__device__ __forceinline__ void gload16(const void* g, void* l) {
    __builtin_amdgcn_global_load_lds(
        (const __attribute__((address_space(1))) unsigned int*)g,
        (__attribute__((address_space(3))) unsigned int*)l,
        16, 0, 0);
}

// ---------------------------------------------------------------------------
// fused fp32 -> bf16 converts (4 tensors, one launch)
// ---------------------------------------------------------------------------
__global__ __launch_bounds__(256)
void f2b_all(const float4* __restrict__ s0, bf16x4* __restrict__ d0, int n0,
             const float4* __restrict__ s1, bf16x4* __restrict__ d1, int n1,
             const float4* __restrict__ s2, bf16x4* __restrict__ d2, int n2,
             const float4* __restrict__ s3, bf16x4* __restrict__ d3, int n3) {
    int j = blockIdx.x * 256 + threadIdx.x;
    const float4* s; bf16x4* d;
    if (j < n0) { s = s0; d = d0; }
    else {
        j -= n0;
        if (j < n1) { s = s1; d = d1; }
        else {
            j -= n1;
            if (j < n2) { s = s2; d = d2; }
            else {
                j -= n2;
                if (j >= n3) return;
                s = s3; d = d3;
            }
        }
    }
    float4 v = s[j];
    bf16x4 o = {(bf16)v.x, (bf16)v.y, (bf16)v.z, (bf16)v.w};
    d[j] = o;
}

// x_proj_w (96 x 2048) -> bf16 padded to 128 rows (rows 96..127 zero)
__global__ __launch_bounds__(256) void f2b_pad_xproj(const float* __restrict__ in,
                                                     bf16* __restrict__ out) {
    int i = blockIdx.x * 256 + threadIdx.x;   // 128*2048 total
    int row = i >> 11, col = i & 2047;
    float v = (row < NPROJ) ? in[row * 2048 + col] : 0.f;
    out[i] = (bf16)v;
}

// ---------------------------------------------------------------------------
// (WM*64) x 128 bf16 MFMA GEMM, BK=64, C = A(MxK) * B(NxK)^T, row-major.
// WM=4 -> 256x128 tile (2 blocks/CU — in_proj); WM=2 -> 128x128 (4 blocks/CU).
// [R8 falsified: atomicAdd split-K epilogue = 2x FETCH (L2 RMW). MODE 3/4 only.]
// grid.z = k-chunks (split-K via partial buffer); z computes [z*K,(z+1)*K).
// MODE 0: store bf16                             (xz)
// MODE 2: softplus(acc + bias[col]) -> bf16      (delta)
// MODE 3: store fp32                             (final out)
// MODE 4: store fp32 partial at z-slice, ld=128  (x_proj split-K)
// ---------------------------------------------------------------------------
template <int MODE, int WM>
__global__ __launch_bounds__(WM * 128, 2)
void gemm_bt(const bf16* __restrict__ A, const bf16* __restrict__ B,
             int M, int N, int K, int lda, int ldb,
             float* __restrict__ outf, bf16* __restrict__ outb,
             const float* __restrict__ bias, int ldout) {
    constexpr int NW      = WM * 2;         // waves per block
    constexpr int A_TILES = WM * 4;         // 16-row fragment tiles of A
    constexpr int B_TILES = 8;
    constexpr int UPW     = (A_TILES + B_TILES) * 2 / NW;  // stage units/wave

    __shared__ bf16 As[A_TILES * 2 * 64 * 8];
    __shared__ bf16 Bs[B_TILES * 2 * 64 * 8];

    const int tid  = threadIdx.x;
    const int wave = tid >> 6;
    const int lane = tid & 63;
    const int l15  = lane & 15;
    const int lk   = lane >> 4;            // 0..3  (k-group)
    const int mBase = blockIdx.y * (WM * 64);
    const int nBase = blockIdx.x * 128;
    const int koff  = blockIdx.z * K;
    const int wm    = wave >> 1;           // 0..WM-1 : 64-row slab
    const int wn    = wave & 1;            // 0..1    : 64-col half

    f32x4 acc[4][4];
    const f32x4 zz = {0.f, 0.f, 0.f, 0.f};
#pragma unroll
    for (int i = 0; i < 4; i++)
#pragma unroll
        for (int j = 0; j < 4; j++) acc[i][j] = zz;

    for (int k0 = 0; k0 < K; k0 += 64) {
#pragma unroll
        for (int u = 0; u < UPW; u++) {
            const int g = wave * UPW + u;
            const int s = g & 1;           // sub-slab (k 0..31 / 32..63)
            const int t = g >> 1;          // fragment-tile index
            if (t < A_TILES) {
                const bf16* gA = A + (size_t)(mBase + t * 16 + l15) * lda
                                   + koff + k0 + s * 32 + lk * 8;
                gload16(gA, &As[((t * 2 + s) * 64 + lane) * 8]);
            } else {
                const int nt = t - A_TILES;
                const bf16* gB = B + (size_t)(nBase + nt * 16 + l15) * ldb
                                   + koff + k0 + s * 32 + lk * 8;
                gload16(gB, &Bs[((nt * 2 + s) * 64 + lane) * 8]);
            }
        }
        __syncthreads();

#pragma unroll
        for (int s = 0; s < 2; s++) {
            bf16x8 af[4], bfr[4];
#pragma unroll
            for (int i = 0; i < 4; i++)
                af[i] = *(const bf16x8*)&As[(((wm * 4 + i) * 2 + s) * 64 + lane) * 8];
#pragma unroll
            for (int j = 0; j < 4; j++)
                bfr[j] = *(const bf16x8*)&Bs[(((wn * 4 + j) * 2 + s) * 64 + lane) * 8];
#pragma unroll
            for (int i = 0; i < 4; i++)
#pragma unroll
                for (int j = 0; j < 4; j++)
                    acc[i][j] = __builtin_amdgcn_mfma_f32_16x16x32_bf16(af[i], bfr[j],
                                                                        acc[i][j], 0, 0, 0);
        }
        __syncthreads();
    }

    // C/D layout (verified m89/m91): col = lane&15, row = (lane>>4)*4 + reg
#pragma unroll
    for (int i = 0; i < 4; i++) {
#pragma unroll
        for (int j = 0; j < 4; j++) {
            const int col = nBase + wn * 64 + j * 16 + l15;
#pragma unroll
            for (int r = 0; r < 4; r++) {
                const int row = mBase + wm * 64 + i * 16 + lk * 4 + r;
                float v = acc[i][j][r];
                if (MODE == 0) {
                    outb[(size_t)row * ldout + col] = (bf16)v;
                } else if (MODE == 2) {
                    float xv = v + bias[col];
                    float sp = fmaxf(xv, 0.f) + log1pf(expf(-fabsf(xv)));
                    outb[(size_t)row * ldout + col] = (bf16)sp;
                } else if (MODE == 3) {
                    outf[(size_t)row * ldout + col] = v;
                } else {  // MODE 4
                    outf[((size_t)blockIdx.z * M + row) * 128 + col] = v;
                }
            }
        }
    }
}

// reduce 4 split-K partials (each [M][128]) -> xdbl fp32 [M][96] + bf16 copy
__global__ __launch_bounds__(256)
void reduce_xproj(const float* __restrict__ part, float* __restrict__ xdbl,
                  bf16* __restrict__ xdbl_b) {
    int i = blockIdx.x * 256 + threadIdx.x;   // M_ROWS * 96
    if (i >= M_ROWS * NPROJ) return;
    int row = i / NPROJ;
    int col = i - row * NPROJ;
    size_t o = (size_t)row * 128 + col;
    float s = part[o] + part[(size_t)M_ROWS * 128 + o]
            + part[(size_t)2 * M_ROWS * 128 + o] + part[(size_t)3 * M_ROWS * 128 + o];
    xdbl[i] = s;
    xdbl_b[i] = (bf16)s;
}

// ---------------------------------------------------------------------------
// causal depthwise conv (k=4) + bias + silu, two channels per thread
// ---------------------------------------------------------------------------
__global__ __launch_bounds__(256)
void conv_silu(const bf16* __restrict__ xz, const float* __restrict__ cw,
               const float* __restrict__ cb, bf16* __restrict__ uact) {
    int i = blockIdx.x * 256 + threadIdx.x;       // b*l*(d/2)
    int dp = i & 1023;                            // channel pair
    int l  = (i >> 10) & (L_SEQ - 1);
    int b  = i >> 22;
    float4 w0 = *(const float4*)&cw[dp * 8];
    float4 w1 = *(const float4*)&cw[dp * 8 + 4];
    const float wv0[4] = {w0.x, w0.y, w0.z, w0.w};
    const float wv1[4] = {w1.x, w1.y, w1.z, w1.w};
    float2 cbv = *(const float2*)&cb[dp * 2];
    float a0 = cbv.x, a1 = cbv.y;
    size_t rb = (size_t)b * L_SEQ;
    const unsigned int* xz32 = (const unsigned int*)xz;  // row stride 2048 dwords
#pragma unroll
    for (int k = 0; k < 4; k++) {
        int li = l - 3 + k;
        if (li >= 0) {
            unsigned int u = xz32[(rb + li) * 2048 + dp];
            float lo = __uint_as_float(u << 16);
            float hi = __uint_as_float(u & 0xFFFF0000u);
            a0 += lo * wv0[k];
            a1 += hi * wv1[k];
        }
    }
    float s0 = a0 / (1.f + expf(-a0));
    float s1 = a1 / (1.f + expf(-a1));
    bf16x2 pk = {(bf16)s0, (bf16)s1};
    ((bf16x2*)uact)[(rb + l) * 1024 + dp] = pk;
}

// ---------------------------------------------------------------------------
// selective scan, chunked 2-pass. NC=64 chunks of LC=64 (R7 config:
// 1024 blocks/pass = 4 blocks/CU — latency-bound loop needs the TLP).
// state layouts (coalesced over d):
//   hloc/h0: [b][c][n][d]   Ssum: [b][c][d]
// Fast path: A_log = log(arange(1..17)) broadcast -> A[d][n] = -(n+1):
// 1 exp + mul chain per step (runtime-verified; generic fallback kept).
// Chunk's B/C rows staged once into LDS.
// ---------------------------------------------------------------------------
__global__ __launch_bounds__(256)
void scan_passA(const bf16* __restrict__ delta, const bf16* __restrict__ uact,
                const float* __restrict__ xdbl, const float* __restrict__ A_log,
                float* __restrict__ hloc, float* __restrict__ Ssum) {
    __shared__ float sB[LC][16];          // 4 KB
    int tid = threadIdx.x, bid = blockIdx.x;
    int d = (bid & 7) * 256 + tid;
    int c = (bid >> 3) & (NC - 1);
    int b = bid >> 9;
    size_t rowb = (size_t)b * L_SEQ + c * LC;
    for (int i = tid; i < LC * 16; i += 256)
        sB[i >> 4][i & 15] = xdbl[(rowb + (i >> 4)) * NPROJ + DT_RANK + (i & 15)];
    float a[16];
    bool regular = true;
#pragma unroll
    for (int n = 0; n < 16; n++) {
        a[n] = expf(A_log[d * 16 + n]);                    // = n+1 expected
        regular = regular && (fabsf(a[n] - (float)(n + 1) * a[0]) < 1e-3f * (n + 1));
    }
    f32x2 h2[8];
#pragma unroll
    for (int k = 0; k < 8; k++) h2[k] = {0.f, 0.f};
    float S = 0.f;
    __syncthreads();

    if (regular) {
        const float na0 = -a[0] * 1.44269504f;             // for exp2
        for (int t = 0; t < LC; t++) {
            size_t r = rowb + t;
            float dt = (float)delta[r * D_INNER + d];
            float u  = (float)uact [r * D_INNER + d];
            S += dt;
            f32x2 du2 = {dt * u, dt * u};
            const f32x2* B2 = (const f32x2*)&sB[t][0];
            float e  = exp2f(dt * na0);                    // e^{-dt*a0}
            float e2 = e * e;
            f32x2 p  = {e, e2};
            f32x2 ee = {e2, e2};
#pragma unroll
            for (int k = 0; k < 8; k++) {
                h2[k] = h2[k] * p + du2 * B2[k];
                p = p * ee;
            }
        }
    } else {
        f32x2 An2[8];
#pragma unroll
        for (int k = 0; k < 8; k++)
            An2[k] = {-a[2 * k] * 1.44269504f, -a[2 * k + 1] * 1.44269504f};
        for (int t = 0; t < LC; t++) {
            size_t r = rowb + t;
            float dt = (float)delta[r * D_INNER + d];
            float u  = (float)uact [r * D_INNER + d];
            S += dt;
            f32x2 du2 = {dt * u, dt * u};
            const f32x2* B2 = (const f32x2*)&sB[t][0];
#pragma unroll
            for (int k = 0; k < 8; k++) {
                f32x2 dA = {exp2f(dt * An2[k][0]), exp2f(dt * An2[k][1])};
                h2[k] = h2[k] * dA + du2 * B2[k];
            }
        }
    }
    size_t cb_ = (size_t)b * NC + c;
#pragma unroll
    for (int k = 0; k < 8; k++) {
        hloc[(cb_ * 16 + 2 * k    ) * D_INNER + d] = h2[k][0];
        hloc[(cb_ * 16 + 2 * k + 1) * D_INNER + d] = h2[k][1];
    }
    Ssum[cb_ * D_INNER + d] = S;
}

// inter-chunk exclusive scan: thread per (b,d,n), d fastest (coalesced)
__global__ __launch_bounds__(256)
void scan_mid(const float* __restrict__ hloc, const float* __restrict__ Ssum,
              const float* __restrict__ A_log, float* __restrict__ h0) {
    int idx = blockIdx.x * 256 + threadIdx.x;   // 65536
    int d = idx & (D_INNER - 1);
    int n = (idx >> 11) & 15;
    int b = idx >> 15;
    float An = -expf(A_log[d * 16 + n]) * 1.44269504f;
    float H = 0.f;
    for (int c = 0; c < NC; c++) {
        size_t cb_ = (size_t)b * NC + c;
        h0[(cb_ * 16 + n) * D_INNER + d] = H;
        H = H * exp2f(Ssum[cb_ * D_INNER + d] * An)
          + hloc[(cb_ * 16 + n) * D_INNER + d];
    }
}

// pass B: recompute h with true h0, emit y = (C.h + u*Dp) * silu(z) as bf16
__global__ __launch_bounds__(256)
void scan_passB(const bf16* __restrict__ delta, const bf16* __restrict__ uact,
                const float* __restrict__ xdbl, const float* __restrict__ A_log,
                const float* __restrict__ h0, const float* __restrict__ Dp,
                const bf16* __restrict__ xz, bf16* __restrict__ y) {
    __shared__ float sBC[LC][32];         // 8 KB: B then C per row
    int tid = threadIdx.x, bid = blockIdx.x;
    int d = (bid & 7) * 256 + tid;
    int c = (bid >> 3) & (NC - 1);
    int b = bid >> 9;
    size_t rowb = (size_t)b * L_SEQ + c * LC;
    for (int i = tid; i < LC * 32; i += 256)
        sBC[i >> 5][i & 31] = xdbl[(rowb + (i >> 5)) * NPROJ + DT_RANK + (i & 31)];
    float a[16];
    bool regular = true;
#pragma unroll
    for (int n = 0; n < 16; n++) {
        a[n] = expf(A_log[d * 16 + n]);
        regular = regular && (fabsf(a[n] - (float)(n + 1) * a[0]) < 1e-3f * (n + 1));
    }
    size_t cb_ = (size_t)b * NC + c;
    f32x2 h2[8];
#pragma unroll
    for (int k = 0; k < 8; k++) {
        h2[k][0] = h0[(cb_ * 16 + 2 * k    ) * D_INNER + d];
        h2[k][1] = h0[(cb_ * 16 + 2 * k + 1) * D_INNER + d];
    }
    float Dd = Dp[d];
    __syncthreads();

    if (regular) {
        const float na0 = -a[0] * 1.44269504f;
        for (int t = 0; t < LC; t++) {
            size_t r = rowb + t;
            float dt = (float)delta[r * D_INNER + d];
            float u  = (float)uact [r * D_INNER + d];
            f32x2 du2 = {dt * u, dt * u};
            const f32x2* B2 = (const f32x2*)&sBC[t][0];
            const f32x2* C2 = (const f32x2*)&sBC[t][16];
            float e  = exp2f(dt * na0);
            float e2 = e * e;
            f32x2 p  = {e, e2};
            f32x2 ee = {e2, e2};
            f32x2 yt2 = {0.f, 0.f};
#pragma unroll
            for (int k = 0; k < 8; k++) {
                h2[k] = h2[k] * p + du2 * B2[k];
                yt2 = yt2 + h2[k] * C2[k];
                p = p * ee;
            }
            float yt = yt2[0] + yt2[1] + u * Dd;
            float z = (float)xz[r * (2 * D_INNER) + D_INNER + d];
            float g = z / (1.f + expf(-z));
            y[r * D_INNER + d] = (bf16)(yt * g);
        }
    } else {
        f32x2 An2[8];
#pragma unroll
        for (int k = 0; k < 8; k++)
            An2[k] = {-a[2 * k] * 1.44269504f, -a[2 * k + 1] * 1.44269504f};
        for (int t = 0; t < LC; t++) {
            size_t r = rowb + t;
            float dt = (float)delta[r * D_INNER + d];
            float u  = (float)uact [r * D_INNER + d];
            f32x2 du2 = {dt * u, dt * u};
            const f32x2* B2 = (const f32x2*)&sBC[t][0];
            const f32x2* C2 = (const f32x2*)&sBC[t][16];
            f32x2 yt2 = {0.f, 0.f};
#pragma unroll
            for (int k = 0; k < 8; k++) {
                f32x2 dA = {exp2f(dt * An2[k][0]), exp2f(dt * An2[k][1])};
                h2[k] = h2[k] * dA + du2 * B2[k];
                yt2 = yt2 + h2[k] * C2[k];
            }
            float yt = yt2[0] + yt2[1] + u * Dd;
            float z = (float)xz[r * (2 * D_INNER) + D_INNER + d];
            float g = z / (1.f + expf(-z));
            y[r * D_INNER + d] = (bf16)(yt * g);
        }
    }
}

// ---------------------------------------------------------------------------
extern "C" void kernel_launch(void* const* d_in, const int* in_sizes, int n_in,
                              void* d_out, int out_size, void* d_ws, size_t ws_size,
                              hipStream_t stream) {
    const float* x         = (const float*)d_in[0];
    const float* in_proj_w = (const float*)d_in[1];
    const float* conv_w    = (const float*)d_in[2];
    const float* conv_b    = (const float*)d_in[3];
    const float* x_proj_w  = (const float*)d_in[4];
    const float* dt_proj_w = (const float*)d_in[5];
    const float* dt_proj_b = (const float*)d_in[6];
    const float* A_log     = (const float*)d_in[7];
    const float* Dp        = (const float*)d_in[8];
    const float* out_proj_w= (const float*)d_in[9];
    float* out             = (float*)d_out;

    char* p = (char*)d_ws;
    auto alloc = [&](size_t bytes) -> char* {
        char* r = p;
        p += (bytes + 255) & ~(size_t)255;
        return r;
    };
    bf16*  x_bf    = (bf16*) alloc((size_t)M_ROWS * D_MODEL * 2);      // 16 MB
    bf16*  w_in    = (bf16*) alloc((size_t)2 * D_INNER * D_MODEL * 2); // 8 MB
    bf16*  w_xp    = (bf16*) alloc((size_t)128 * D_INNER * 2);         // 0.5 MB
    bf16*  w_dt    = (bf16*) alloc((size_t)D_INNER * DT_RANK * 2);     // 0.25 MB
    bf16*  w_out   = (bf16*) alloc((size_t)D_MODEL * D_INNER * 2);     // 4 MB
    bf16*  xz      = (bf16*) alloc((size_t)M_ROWS * 2 * D_INNER * 2);  // 64 MB
    bf16*  uact    = (bf16*) alloc((size_t)M_ROWS * D_INNER * 2);      // 32 MB
    float* xdbl    = (float*)alloc((size_t)M_ROWS * NPROJ * 4);        // 3 MB
    bf16*  xdbl_b  = (bf16*) alloc((size_t)M_ROWS * NPROJ * 2);        // 1.5 MB
    bf16*  deltab  = (bf16*) alloc((size_t)M_ROWS * D_INNER * 2);      // 32 MB
    float* hloc    = (float*)alloc((size_t)B_SZ * NC * 16 * D_INNER * 4); // 16 MB
    float* Ssum    = (float*)alloc((size_t)B_SZ * NC * D_INNER * 4);   // 2 MB
    float* h0      = (float*)alloc((size_t)B_SZ * NC * 16 * D_INNER * 4); // 16 MB
    bf16*  ybf     = (bf16*) alloc((size_t)M_ROWS * D_INNER * 2);      // 32 MB
    float* partial = (float*)alloc((size_t)4 * M_ROWS * 128 * 4);      // 16 MB

    // 1) converts (one fused launch + xproj pad)
    {
        const int n0 = M_ROWS * D_MODEL / 4;          // x
        const int n1 = 2 * D_INNER * D_MODEL / 4;     // in_proj_w
        const int n2 = D_INNER * DT_RANK / 4;         // dt_proj_w
        const int n3 = D_MODEL * D_INNER / 4;         // out_proj_w
        const int nt = n0 + n1 + n2 + n3;
        f2b_all<<<(nt + 255) / 256, 256, 0, stream>>>(
            (const float4*)x, (bf16x4*)x_bf, n0,
            (const float4*)in_proj_w, (bf16x4*)w_in, n1,
            (const float4*)dt_proj_w, (bf16x4*)w_dt, n2,
            (const float4*)out_proj_w, (bf16x4*)w_out, n3);
        f2b_pad_xproj<<<(128 * D_INNER) / 256, 256, 0, stream>>>(x_proj_w, w_xp);
    }

    // 2) in_proj: xz = x @ in_proj_w^T   (8192 x 4096, K=1024), 256x128 tiles
    gemm_bt<0, 4><<<dim3(2 * D_INNER / 128, M_ROWS / 256, 1), 512, 0, stream>>>(
        x_bf, w_in, M_ROWS, 2 * D_INNER, D_MODEL, D_MODEL, D_MODEL,
        nullptr, xz, nullptr, 2 * D_INNER);

    // 3) conv + silu -> u_act
    conv_silu<<<(M_ROWS * D_INNER / 2) / 256, 256, 0, stream>>>(xz, conv_w, conv_b, uact);

    // 4) x_proj split-K(4): partials = u_act @ x_proj_w^T  (8192 x 128, K=4x512)
    gemm_bt<4, 2><<<dim3(1, M_ROWS / 128, 4), 256, 0, stream>>>(
        uact, w_xp, M_ROWS, 128, 512, D_INNER, D_INNER,
        partial, nullptr, nullptr, 128);
    reduce_xproj<<<(M_ROWS * NPROJ + 255) / 256, 256, 0, stream>>>(partial, xdbl, xdbl_b);

    // 5) dt: delta = softplus(x_dbl[:, :64] @ dt_proj_w^T + b)
    //    K=64 single-iter -> WM=2, 1024 blocks = 4/CU
    gemm_bt<2, 2><<<dim3(D_INNER / 128, M_ROWS / 128, 1), 256, 0, stream>>>(
        xdbl_b, w_dt, M_ROWS, D_INNER, DT_RANK, NPROJ, DT_RANK,
        nullptr, deltab, dt_proj_b, D_INNER);

    // 6) scan (NC=64 chunks of LC=64; 1024 blocks/pass = 4 blocks/CU)
    scan_passA<<<B_SZ * NC * (D_INNER / 256), 256, 0, stream>>>(
        deltab, uact, xdbl, A_log, hloc, Ssum);
    scan_mid<<<(B_SZ * D_INNER * 16) / 256, 256, 0, stream>>>(hloc, Ssum, A_log, h0);
    scan_passB<<<B_SZ * NC * (D_INNER / 256), 256, 0, stream>>>(
        deltab, uact, xdbl, A_log, h0, Dp, xz, ybf);

    // 7) out_proj -> d_out (fp32), 128x128 tiles, 512 blocks = 2/CU (R7 form)
    gemm_bt<3, 2><<<dim3(D_MODEL / 128, M_ROWS / 128, 1), 256, 0, stream>>>(
        ybf, w_out, M_ROWS, D_MODEL, D_INNER, D_INNER, D_INNER,
        out, nullptr, nullptr, D_MODEL);

    (void)in_sizes; (void)n_in; (void)out_size; (void)ws_size;
}

// Round 11
// 489.309 us; speedup vs baseline: 1.1599x; 1.0117x over previous
//
#include <hip/hip_runtime.h>

#define D_MODEL  1024
#define D_STATE  16
#define D_CONV   4
#define D_INNER  2048
#define DT_RANK  64
#define B_SZ     2
#define L_SEQ    4096
#define NPROJ    96                 // DT_RANK + 2*D_STATE
#define M_ROWS   (B_SZ * L_SEQ)     // 8192
#define NC       64                 // chunks over L (R9 falsified NC=32: scan is
#define LC       64                 //  latency-bound; TLP > state-traffic saving)

typedef __bf16 bf16;
typedef __bf16 bf16x8 __attribute__((ext_vector_type(8)));
typedef __bf16 bf16x4 __attribute__((ext_vector_type(4)));
typedef __bf16 bf16x2 __attribute__((ext_vector_type(2)));
typedef float  f32x4  __attribute__((ext_vector_type(4)));
typedef float  f32x2  __attribute__((ext_vector_type(2)));

// ---------------------------------------------------------------------------
// async global -> LDS, 16B per lane (wave-uniform LDS base + lane*16)
// ---------------------------------------------------------------------------
__device__ __forceinline__ void gload16(const void* g, void* l) {
    __builtin_amdgcn_global_load_lds(
        (const __attribute__((address_space(1))) unsigned int*)g,
        (__attribute__((address_space(3))) unsigned int*)l,
        16, 0, 0);
}

// ---------------------------------------------------------------------------
// fused fp32 -> bf16 converts (4 tensors, one launch)
// ---------------------------------------------------------------------------
__global__ __launch_bounds__(256)
void f2b_all(const float4* __restrict__ s0, bf16x4* __restrict__ d0, int n0,
             const float4* __restrict__ s1, bf16x4* __restrict__ d1, int n1,
             const float4* __restrict__ s2, bf16x4* __restrict__ d2, int n2,
             const float4* __restrict__ s3, bf16x4* __restrict__ d3, int n3) {
    int j = blockIdx.x * 256 + threadIdx.x;
    const float4* s; bf16x4* d;
    if (j < n0) { s = s0; d = d0; }
    else {
        j -= n0;
        if (j < n1) { s = s1; d = d1; }
        else {
            j -= n1;
            if (j < n2) { s = s2; d = d2; }
            else {
                j -= n2;
                if (j >= n3) return;
                s = s3; d = d3;
            }
        }
    }
    float4 v = s[j];
    bf16x4 o = {(bf16)v.x, (bf16)v.y, (bf16)v.z, (bf16)v.w};
    d[j] = o;
}

// x_proj_w (96 x 2048) -> bf16 padded to 128 rows (rows 96..127 zero)
__global__ __launch_bounds__(256) void f2b_pad_xproj(const float* __restrict__ in,
                                                     bf16* __restrict__ out) {
    int i = blockIdx.x * 256 + threadIdx.x;   // 128*2048 total
    int row = i >> 11, col = i & 2047;
    float v = (row < NPROJ) ? in[row * 2048 + col] : 0.f;
    out[i] = (bf16)v;
}

// ---------------------------------------------------------------------------
// (WM*64) x 128 bf16 MFMA GEMM, BK=64, C = A(MxK) * B(NxK)^T, row-major.
// WM=4 -> 256x128 (2 blocks/CU — in_proj); WM=2 -> 128x128 (4/CU cap);
// WM=1 -> 64x128 (R11: fills CUs when the natural grid is small — out_proj).
// [R8 falsified: atomicAdd split-K epilogue = 2x FETCH (L2 RMW). MODE 3/4 only.]
// grid.z = k-chunks (split-K via partial buffer); z computes [z*K,(z+1)*K).
// MODE 0: store bf16                             (xz)
// MODE 2: softplus(acc + bias[col]) -> bf16      (delta)
// MODE 3: store fp32                             (final out)
// MODE 4: store fp32 partial at z-slice, ld=128  (x_proj split-K)
// ---------------------------------------------------------------------------
template <int MODE, int WM>
__global__ __launch_bounds__(WM * 128, 2)
void gemm_bt(const bf16* __restrict__ A, const bf16* __restrict__ B,
             int M, int N, int K, int lda, int ldb,
             float* __restrict__ outf, bf16* __restrict__ outb,
             const float* __restrict__ bias, int ldout) {
    constexpr int NW      = WM * 2;         // waves per block
    constexpr int A_TILES = WM * 4;         // 16-row fragment tiles of A
    constexpr int B_TILES = 8;
    constexpr int UPW     = (A_TILES + B_TILES) * 2 / NW;  // stage units/wave

    __shared__ bf16 As[A_TILES * 2 * 64 * 8];
    __shared__ bf16 Bs[B_TILES * 2 * 64 * 8];

    const int tid  = threadIdx.x;
    const int wave = tid >> 6;
    const int lane = tid & 63;
    const int l15  = lane & 15;
    const int lk   = lane >> 4;            // 0..3  (k-group)
    const int mBase = blockIdx.y * (WM * 64);
    const int nBase = blockIdx.x * 128;
    const int koff  = blockIdx.z * K;
    const int wm    = wave >> 1;           // 0..WM-1 : 64-row slab
    const int wn    = wave & 1;            // 0..1    : 64-col half

    f32x4 acc[4][4];
    const f32x4 zz = {0.f, 0.f, 0.f, 0.f};
#pragma unroll
    for (int i = 0; i < 4; i++)
#pragma unroll
        for (int j = 0; j < 4; j++) acc[i][j] = zz;

    for (int k0 = 0; k0 < K; k0 += 64) {
#pragma unroll
        for (int u = 0; u < UPW; u++) {
            const int g = wave * UPW + u;
            const int s = g & 1;           // sub-slab (k 0..31 / 32..63)
            const int t = g >> 1;          // fragment-tile index
            if (t < A_TILES) {
                const bf16* gA = A + (size_t)(mBase + t * 16 + l15) * lda
                                   + koff + k0 + s * 32 + lk * 8;
                gload16(gA, &As[((t * 2 + s) * 64 + lane) * 8]);
            } else {
                const int nt = t - A_TILES;
                const bf16* gB = B + (size_t)(nBase + nt * 16 + l15) * ldb
                                   + koff + k0 + s * 32 + lk * 8;
                gload16(gB, &Bs[((nt * 2 + s) * 64 + lane) * 8]);
            }
        }
        __syncthreads();

#pragma unroll
        for (int s = 0; s < 2; s++) {
            bf16x8 af[4], bfr[4];
#pragma unroll
            for (int i = 0; i < 4; i++)
                af[i] = *(const bf16x8*)&As[(((wm * 4 + i) * 2 + s) * 64 + lane) * 8];
#pragma unroll
            for (int j = 0; j < 4; j++)
                bfr[j] = *(const bf16x8*)&Bs[(((wn * 4 + j) * 2 + s) * 64 + lane) * 8];
#pragma unroll
            for (int i = 0; i < 4; i++)
#pragma unroll
                for (int j = 0; j < 4; j++)
                    acc[i][j] = __builtin_amdgcn_mfma_f32_16x16x32_bf16(af[i], bfr[j],
                                                                        acc[i][j], 0, 0, 0);
        }
        __syncthreads();
    }

    // C/D layout (verified m89/m91): col = lane&15, row = (lane>>4)*4 + reg
#pragma unroll
    for (int i = 0; i < 4; i++) {
#pragma unroll
        for (int j = 0; j < 4; j++) {
            const int col = nBase + wn * 64 + j * 16 + l15;
#pragma unroll
            for (int r = 0; r < 4; r++) {
                const int row = mBase + wm * 64 + i * 16 + lk * 4 + r;
                float v = acc[i][j][r];
                if (MODE == 0) {
                    outb[(size_t)row * ldout + col] = (bf16)v;
                } else if (MODE == 2) {
                    float xv = v + bias[col];
                    float sp = fmaxf(xv, 0.f) + log1pf(expf(-fabsf(xv)));
                    outb[(size_t)row * ldout + col] = (bf16)sp;
                } else if (MODE == 3) {
                    outf[(size_t)row * ldout + col] = v;
                } else {  // MODE 4
                    outf[((size_t)blockIdx.z * M + row) * 128 + col] = v;
                }
            }
        }
    }
}

// reduce 4 split-K partials (each [M][128]) -> xdbl fp32 [M][96] + bf16 copy
__global__ __launch_bounds__(256)
void reduce_xproj(const float* __restrict__ part, float* __restrict__ xdbl,
                  bf16* __restrict__ xdbl_b) {
    int i = blockIdx.x * 256 + threadIdx.x;   // M_ROWS * 96
    if (i >= M_ROWS * NPROJ) return;
    int row = i / NPROJ;
    int col = i - row * NPROJ;
    size_t o = (size_t)row * 128 + col;
    float s = part[o] + part[(size_t)M_ROWS * 128 + o]
            + part[(size_t)2 * M_ROWS * 128 + o] + part[(size_t)3 * M_ROWS * 128 + o];
    xdbl[i] = s;
    xdbl_b[i] = (bf16)s;
}

// ---------------------------------------------------------------------------
// causal depthwise conv (k=4) + bias + silu.
// R11: sliding window — each thread produces 4 consecutive l outputs for a
// channel pair: 7 row-loads for 8 outputs (was 16 for 2) -> ~88 MB total
// traffic vs ~160 MB.
// ---------------------------------------------------------------------------
__global__ __launch_bounds__(256)
void conv_silu(const bf16* __restrict__ xz, const float* __restrict__ cw,
               const float* __restrict__ cb, bf16* __restrict__ uact) {
    int i = blockIdx.x * 256 + threadIdx.x;       // b*(l/4)*(d/2) = 2M threads
    int dp = i & 1023;                            // channel pair
    int l4 = (i >> 10) & 1023;                    // l quad
    int b  = i >> 20;
    const int l0 = l4 * 4;
    float4 w0 = *(const float4*)&cw[dp * 8];
    float4 w1 = *(const float4*)&cw[dp * 8 + 4];
    const float wv0[4] = {w0.x, w0.y, w0.z, w0.w};
    const float wv1[4] = {w1.x, w1.y, w1.z, w1.w};
    float2 cbv = *(const float2*)&cb[dp * 2];
    size_t rb = (size_t)b * L_SEQ;
    const unsigned int* xz32 = (const unsigned int*)xz;  // row stride 2048 dwords
    float flo[7], fhi[7];
#pragma unroll
    for (int k = 0; k < 7; k++) {
        int li = l0 - 3 + k;
        unsigned int u = (li >= 0) ? xz32[(rb + li) * 2048 + dp] : 0u;
        flo[k] = __uint_as_float(u << 16);
        fhi[k] = __uint_as_float(u & 0xFFFF0000u);
    }
#pragma unroll
    for (int t = 0; t < 4; t++) {
        float a0 = cbv.x, a1 = cbv.y;
#pragma unroll
        for (int k = 0; k < 4; k++) {
            a0 += flo[t + k] * wv0[k];
            a1 += fhi[t + k] * wv1[k];
        }
        float s0 = a0 / (1.f + expf(-a0));
        float s1 = a1 / (1.f + expf(-a1));
        bf16x2 pk = {(bf16)s0, (bf16)s1};
        ((bf16x2*)uact)[(rb + l0 + t) * 1024 + dp] = pk;
    }
}

// ---------------------------------------------------------------------------
// selective scan, chunked 2-pass. NC=64 chunks of LC=64 (1024 blocks/pass =
// 4 blocks/CU — latency-bound loop needs the TLP; R9 falsified NC=32).
// state layouts (coalesced over d):
//   hloc/h0: [b][c][n][d]   Ssum: [b][c][d]
// Fast path: A_log = log(arange(1..17)) broadcast -> A[d][n] = -(n+1):
// 1 exp + mul chain per step (runtime-verified; generic fallback kept).
// Chunk's B/C rows staged once into LDS.
// ---------------------------------------------------------------------------
__global__ __launch_bounds__(256)
void scan_passA(const bf16* __restrict__ delta, const bf16* __restrict__ uact,
                const float* __restrict__ xdbl, const float* __restrict__ A_log,
                float* __restrict__ hloc, float* __restrict__ Ssum) {
    __shared__ float sB[LC][16];          // 4 KB
    int tid = threadIdx.x, bid = blockIdx.x;
    int d = (bid & 7) * 256 + tid;
    int c = (bid >> 3) & (NC - 1);
    int b = bid >> 9;
    size_t rowb = (size_t)b * L_SEQ + c * LC;
    for (int i = tid; i < LC * 16; i += 256)
        sB[i >> 4][i & 15] = xdbl[(rowb + (i >> 4)) * NPROJ + DT_RANK + (i & 15)];
    float a[16];
    bool regular = true;
#pragma unroll
    for (int n = 0; n < 16; n++) {
        a[n] = expf(A_log[d * 16 + n]);                    // = n+1 expected
        regular = regular && (fabsf(a[n] - (float)(n + 1) * a[0]) < 1e-3f * (n + 1));
    }
    f32x2 h2[8];
#pragma unroll
    for (int k = 0; k < 8; k++) h2[k] = {0.f, 0.f};
    float S = 0.f;
    __syncthreads();

    if (regular) {
        const float na0 = -a[0] * 1.44269504f;             // for exp2
        for (int t = 0; t < LC; t++) {
            size_t r = rowb + t;
            float dt = (float)delta[r * D_INNER + d];
            float u  = (float)uact [r * D_INNER + d];
            S += dt;
            f32x2 du2 = {dt * u, dt * u};
            const f32x2* B2 = (const f32x2*)&sB[t][0];
            float e  = exp2f(dt * na0);                    // e^{-dt*a0}
            float e2 = e * e;
            f32x2 p  = {e, e2};
            f32x2 ee = {e2, e2};
#pragma unroll
            for (int k = 0; k < 8; k++) {
                h2[k] = h2[k] * p + du2 * B2[k];
                p = p * ee;
            }
        }
    } else {
        f32x2 An2[8];
#pragma unroll
        for (int k = 0; k < 8; k++)
            An2[k] = {-a[2 * k] * 1.44269504f, -a[2 * k + 1] * 1.44269504f};
        for (int t = 0; t < LC; t++) {
            size_t r = rowb + t;
            float dt = (float)delta[r * D_INNER + d];
            float u  = (float)uact [r * D_INNER + d];
            S += dt;
            f32x2 du2 = {dt * u, dt * u};
            const f32x2* B2 = (const f32x2*)&sB[t][0];
#pragma unroll
            for (int k = 0; k < 8; k++) {
                f32x2 dA = {exp2f(dt * An2[k][0]), exp2f(dt * An2[k][1])};
                h2[k] = h2[k] * dA + du2 * B2[k];
            }
        }
    }
    size_t cb_ = (size_t)b * NC + c;
#pragma unroll
    for (int k = 0; k < 8; k++) {
        hloc[(cb_ * 16 + 2 * k    ) * D_INNER + d] = h2[k][0];
        hloc[(cb_ * 16 + 2 * k + 1) * D_INNER + d] = h2[k][1];
    }
    Ssum[cb_ * D_INNER + d] = S;
}

// inter-chunk exclusive scan: thread per (b,d,n), d fastest (coalesced)
__global__ __launch_bounds__(256)
void scan_mid(const float* __restrict__ hloc, const float* __restrict__ Ssum,
              const float* __restrict__ A_log, float* __restrict__ h0) {
    int idx = blockIdx.x * 256 + threadIdx.x;   // 65536
    int d = idx & (D_INNER - 1);
    int n = (idx >> 11) & 15;
    int b = idx >> 15;
    float An = -expf(A_log[d * 16 + n]) * 1.44269504f;
    float H = 0.f;
    for (int c = 0; c < NC; c++) {
        size_t cb_ = (size_t)b * NC + c;
        h0[(cb_ * 16 + n) * D_INNER + d] = H;
        H = H * exp2f(Ssum[cb_ * D_INNER + d] * An)
          + hloc[(cb_ * 16 + n) * D_INNER + d];
    }
}

// pass B: recompute h with true h0, emit y = (C.h + u*Dp) * silu(z) as bf16
__global__ __launch_bounds__(256)
void scan_passB(const bf16* __restrict__ delta, const bf16* __restrict__ uact,
                const float* __restrict__ xdbl, const float* __restrict__ A_log,
                const float* __restrict__ h0, const float* __restrict__ Dp,
                const bf16* __restrict__ xz, bf16* __restrict__ y) {
    __shared__ float sBC[LC][32];         // 8 KB: B then C per row
    int tid = threadIdx.x, bid = blockIdx.x;
    int d = (bid & 7) * 256 + tid;
    int c = (bid >> 3) & (NC - 1);
    int b = bid >> 9;
    size_t rowb = (size_t)b * L_SEQ + c * LC;
    for (int i = tid; i < LC * 32; i += 256)
        sBC[i >> 5][i & 31] = xdbl[(rowb + (i >> 5)) * NPROJ + DT_RANK + (i & 31)];
    float a[16];
    bool regular = true;
#pragma unroll
    for (int n = 0; n < 16; n++) {
        a[n] = expf(A_log[d * 16 + n]);
        regular = regular && (fabsf(a[n] - (float)(n + 1) * a[0]) < 1e-3f * (n + 1));
    }
    size_t cb_ = (size_t)b * NC + c;
    f32x2 h2[8];
#pragma unroll
    for (int k = 0; k < 8; k++) {
        h2[k][0] = h0[(cb_ * 16 + 2 * k    ) * D_INNER + d];
        h2[k][1] = h0[(cb_ * 16 + 2 * k + 1) * D_INNER + d];
    }
    float Dd = Dp[d];
    __syncthreads();

    if (regular) {
        const float na0 = -a[0] * 1.44269504f;
        for (int t = 0; t < LC; t++) {
            size_t r = rowb + t;
            float dt = (float)delta[r * D_INNER + d];
            float u  = (float)uact [r * D_INNER + d];
            f32x2 du2 = {dt * u, dt * u};
            const f32x2* B2 = (const f32x2*)&sBC[t][0];
            const f32x2* C2 = (const f32x2*)&sBC[t][16];
            float e  = exp2f(dt * na0);
            float e2 = e * e;
            f32x2 p  = {e, e2};
            f32x2 ee = {e2, e2};
            f32x2 yt2 = {0.f, 0.f};
#pragma unroll
            for (int k = 0; k < 8; k++) {
                h2[k] = h2[k] * p + du2 * B2[k];
                yt2 = yt2 + h2[k] * C2[k];
                p = p * ee;
            }
            float yt = yt2[0] + yt2[1] + u * Dd;
            float z = (float)xz[r * (2 * D_INNER) + D_INNER + d];
            float g = z / (1.f + expf(-z));
            y[r * D_INNER + d] = (bf16)(yt * g);
        }
    } else {
        f32x2 An2[8];
#pragma unroll
        for (int k = 0; k < 8; k++)
            An2[k] = {-a[2 * k] * 1.44269504f, -a[2 * k + 1] * 1.44269504f};
        for (int t = 0; t < LC; t++) {
            size_t r = rowb + t;
            float dt = (float)delta[r * D_INNER + d];
            float u  = (float)uact [r * D_INNER + d];
            f32x2 du2 = {dt * u, dt * u};
            const f32x2* B2 = (const f32x2*)&sBC[t][0];
            const f32x2* C2 = (const f32x2*)&sBC[t][16];
            f32x2 yt2 = {0.f, 0.f};
#pragma unroll
            for (int k = 0; k < 8; k++) {
                f32x2 dA = {exp2f(dt * An2[k][0]), exp2f(dt * An2[k][1])};
                h2[k] = h2[k] * dA + du2 * B2[k];
                yt2 = yt2 + h2[k] * C2[k];
            }
            float yt = yt2[0] + yt2[1] + u * Dd;
            float z = (float)xz[r * (2 * D_INNER) + D_INNER + d];
            float g = z / (1.f + expf(-z));
            y[r * D_INNER + d] = (bf16)(yt * g);
        }
    }
}

// ---------------------------------------------------------------------------
extern "C" void kernel_launch(void* const* d_in, const int* in_sizes, int n_in,
                              void* d_out, int out_size, void* d_ws, size_t ws_size,
                              hipStream_t stream) {
    const float* x         = (const float*)d_in[0];
    const float* in_proj_w = (const float*)d_in[1];
    const float* conv_w    = (const float*)d_in[2];
    const float* conv_b    = (const float*)d_in[3];
    const float* x_proj_w  = (const float*)d_in[4];
    const float* dt_proj_w = (const float*)d_in[5];
    const float* dt_proj_b = (const float*)d_in[6];
    const float* A_log     = (const float*)d_in[7];
    const float* Dp        = (const float*)d_in[8];
    const float* out_proj_w= (const float*)d_in[9];
    float* out             = (float*)d_out;

    char* p = (char*)d_ws;
    auto alloc = [&](size_t bytes) -> char* {
        char* r = p;
        p += (bytes + 255) & ~(size_t)255;
        return r;
    };
    bf16*  x_bf    = (bf16*) alloc((size_t)M_ROWS * D_MODEL * 2);      // 16 MB
    bf16*  w_in    = (bf16*) alloc((size_t)2 * D_INNER * D_MODEL * 2); // 8 MB
    bf16*  w_xp    = (bf16*) alloc((size_t)128 * D_INNER * 2);         // 0.5 MB
    bf16*  w_dt    = (bf16*) alloc((size_t)D_INNER * DT_RANK * 2);     // 0.25 MB
    bf16*  w_out   = (bf16*) alloc((size_t)D_MODEL * D_INNER * 2);     // 4 MB
    bf16*  xz      = (bf16*) alloc((size_t)M_ROWS * 2 * D_INNER * 2);  // 64 MB
    bf16*  uact    = (bf16*) alloc((size_t)M_ROWS * D_INNER * 2);      // 32 MB
    float* xdbl    = (float*)alloc((size_t)M_ROWS * NPROJ * 4);        // 3 MB
    bf16*  xdbl_b  = (bf16*) alloc((size_t)M_ROWS * NPROJ * 2);        // 1.5 MB
    bf16*  deltab  = (bf16*) alloc((size_t)M_ROWS * D_INNER * 2);      // 32 MB
    float* hloc    = (float*)alloc((size_t)B_SZ * NC * 16 * D_INNER * 4); // 16 MB
    float* Ssum    = (float*)alloc((size_t)B_SZ * NC * D_INNER * 4);   // 2 MB
    float* h0      = (float*)alloc((size_t)B_SZ * NC * 16 * D_INNER * 4); // 16 MB
    bf16*  ybf     = (bf16*) alloc((size_t)M_ROWS * D_INNER * 2);      // 32 MB
    float* partial = (float*)alloc((size_t)4 * M_ROWS * 128 * 4);      // 16 MB

    // 1) converts (one fused launch + xproj pad)
    {
        const int n0 = M_ROWS * D_MODEL / 4;          // x
        const int n1 = 2 * D_INNER * D_MODEL / 4;     // in_proj_w
        const int n2 = D_INNER * DT_RANK / 4;         // dt_proj_w
        const int n3 = D_MODEL * D_INNER / 4;         // out_proj_w
        const int nt = n0 + n1 + n2 + n3;
        f2b_all<<<(nt + 255) / 256, 256, 0, stream>>>(
            (const float4*)x, (bf16x4*)x_bf, n0,
            (const float4*)in_proj_w, (bf16x4*)w_in, n1,
            (const float4*)dt_proj_w, (bf16x4*)w_dt, n2,
            (const float4*)out_proj_w, (bf16x4*)w_out, n3);
        f2b_pad_xproj<<<(128 * D_INNER) / 256, 256, 0, stream>>>(x_proj_w, w_xp);
    }

    // 2) in_proj: xz = x @ in_proj_w^T   (8192 x 4096, K=1024), 256x128 tiles
    gemm_bt<0, 4><<<dim3(2 * D_INNER / 128, M_ROWS / 256, 1), 512, 0, stream>>>(
        x_bf, w_in, M_ROWS, 2 * D_INNER, D_MODEL, D_MODEL, D_MODEL,
        nullptr, xz, nullptr, 2 * D_INNER);

    // 3) conv + silu -> u_act (sliding window, 4 l-outputs per thread)
    conv_silu<<<(B_SZ * (L_SEQ / 4) * (D_INNER / 2)) / 256, 256, 0, stream>>>(
        xz, conv_w, conv_b, uact);

    // 4) x_proj split-K(4): partials = u_act @ x_proj_w^T  (8192 x 128, K=4x512)
    gemm_bt<4, 2><<<dim3(1, M_ROWS / 128, 4), 256, 0, stream>>>(
        uact, w_xp, M_ROWS, 128, 512, D_INNER, D_INNER,
        partial, nullptr, nullptr, 128);
    reduce_xproj<<<(M_ROWS * NPROJ + 255) / 256, 256, 0, stream>>>(partial, xdbl, xdbl_b);

    // 5) dt: delta = softplus(x_dbl[:, :64] @ dt_proj_w^T + b)
    //    K=64 single-iter -> WM=2, 1024 blocks = 4/CU
    gemm_bt<2, 2><<<dim3(D_INNER / 128, M_ROWS / 128, 1), 256, 0, stream>>>(
        xdbl_b, w_dt, M_ROWS, D_INNER, DT_RANK, NPROJ, DT_RANK,
        nullptr, deltab, dt_proj_b, D_INNER);

    // 6) scan (NC=64 chunks of LC=64; 1024 blocks/pass = 4 blocks/CU)
    scan_passA<<<B_SZ * NC * (D_INNER / 256), 256, 0, stream>>>(
        deltab, uact, xdbl, A_log, hloc, Ssum);
    scan_mid<<<(B_SZ * D_INNER * 16) / 256, 256, 0, stream>>>(hloc, Ssum, A_log, h0);
    scan_passB<<<B_SZ * NC * (D_INNER / 256), 256, 0, stream>>>(
        deltab, uact, xdbl, A_log, h0, Dp, xz, ybf);

    // 7) out_proj -> d_out (fp32), 64x128 tiles: 1024 blocks = 4/CU resident
    //    (R11 experiment: fills CU occupancy capacity; 512-block WM=2 left
    //     half the barrier-group overlap idle)
    gemm_bt<3, 1><<<dim3(D_MODEL / 128, M_ROWS / 64, 1), 128, 0, stream>>>(
        ybf, w_out, M_ROWS, D_MODEL, D_INNER, D_INNER, D_INNER,
        out, nullptr, nullptr, D_MODEL);

    (void)in_sizes; (void)n_in; (void)out_size; (void)ws_size;
}